// Round 7
// baseline (429.884 us; speedup 1.0000x reference)
//
#include <hip/hip_runtime.h>
#include <cstddef>

#define SQLEN 2048
#define DMODEL 2048
#define NHEADS 16
#define DHEAD 128

typedef __attribute__((ext_vector_type(8))) short bf16x8;
typedef __attribute__((ext_vector_type(4))) float floatx4;

__device__ __forceinline__ unsigned short f2bf(float f) {
  union { float f; unsigned u; } c; c.f = f;
  unsigned u = c.u;
  unsigned r = u + 0x7fffu + ((u >> 16) & 1u);
  return (unsigned short)(r >> 16);
}
__device__ __forceinline__ float bf2f(unsigned short s) {
  union { unsigned u; float f; } c; c.u = ((unsigned)s) << 16;
  return c.f;
}

// ---------------- fp32 -> bf16 convert (vectorized) -------------------------
__global__ __launch_bounds__(256) void f2b_kernel(const float4* __restrict__ in,
                                                  ushort4* __restrict__ out) {
  int i = blockIdx.x * 256 + threadIdx.x;
  float4 v = in[i];
  ushort4 o;
  o.x = f2bf(v.x); o.y = f2bf(v.y); o.z = f2bf(v.z); o.w = f2bf(v.w);
  out[i] = o;
}

// two-array variant (two tensors in one launch)
__global__ __launch_bounds__(256) void f2b2_kernel(const float4* __restrict__ in0,
                                                   ushort4* __restrict__ out0,
                                                   const float4* __restrict__ in1,
                                                   ushort4* __restrict__ out1,
                                                   int half_blocks) {
  int b = blockIdx.x;
  const float4* in = (b < half_blocks) ? in0 : in1;
  ushort4* out = (b < half_blocks) ? out0 : out1;
  int i = (b < half_blocks ? b : b - half_blocks) * 256 + threadIdx.x;
  float4 v = in[i];
  ushort4 o;
  o.x = f2bf(v.x); o.y = f2bf(v.y); o.z = f2bf(v.z); o.w = f2bf(v.w);
  out[i] = o;
}

// ---------------- zero fp32 buffer ------------------------------------------
__global__ __launch_bounds__(256) void zero_kernel(float4* __restrict__ p) {
  p[blockIdx.x * 256 + threadIdx.x] = (float4){0.f, 0.f, 0.f, 0.f};
}

// =================== 256x256 8-phase bf16 GEMM (C = A @ B^T) ================
#define GLD(srcp, dstp) __builtin_amdgcn_global_load_lds( \
    (const __attribute__((address_space(1))) unsigned int*)(srcp), \
    (__attribute__((address_space(3))) unsigned int*)(dstp), 16, 0, 0)

__global__ __launch_bounds__(512, 2) void gemm256_nt(const unsigned short* __restrict__ A,
                                                     const unsigned short* __restrict__ B,
                                                     float* __restrict__ C,
                                                     int M, int N, int K) {
  __shared__ __align__(16) unsigned short lds[65536];  // 128 KiB
  int tid = threadIdx.x;
  int wave = tid >> 6, lane = tid & 63;
  int wm = wave >> 2, wn = wave & 3;            // 2 x 4 wave grid
  int quad = lane >> 4, m16 = lane & 15;
  int sw = m16 & 7;

  int nTN = gridDim.x;
  int lin = blockIdx.y * nTN + blockIdx.x;
  int nwg = gridDim.x * gridDim.y;
  int swzb = (nwg & 7) == 0 ? ((lin & 7) * (nwg >> 3) + (lin >> 3)) : lin;
  int row0 = (swzb / nTN) * 256, col0 = (swzb % nTN) * 256;

  const int nkt = K >> 6;    // K-tiles of 64
  const int nit = K >> 7;    // loop iters (2 tiles each)

  int srow = tid >> 3;
  int scol8 = (((tid & 7) ^ ((tid >> 3) & 7)) * 8);  // pre-swizzled global col

  bf16x8 a0[2][4], a1[2][4], bb[2][2];
  floatx4 acc[2][2][4][2];
#pragma unroll
  for (int a = 0; a < 2; a++)
#pragma unroll
    for (int b = 0; b < 2; b++)
#pragma unroll
      for (int c = 0; c < 4; c++)
#pragma unroll
        for (int d = 0; d < 2; d++) acc[a][b][c][d] = (floatx4){0.f, 0.f, 0.f, 0.f};

#define STAGE(t_, ab_, h_) do { \
    int t2_ = (t_); if (t2_ >= nkt) t2_ -= nkt; \
    const unsigned short* gp_ = (ab_) ? B : A; \
    int rb_ = ((ab_) ? col0 : row0) + (h_) * 128 + srow; \
    int kk_ = t2_ * 64 + scol8; \
    unsigned bs_ = ((unsigned)((t_) & 1)) * 32768u + (ab_) * 16384u + (h_) * 8192u; \
    GLD(gp_ + (size_t)rb_ * K + kk_, lds + bs_ + tid * 8); \
    GLD(gp_ + (size_t)(rb_ + 64) * K + kk_, lds + bs_ + 4096 + tid * 8); \
  } while (0)

#define VMW asm volatile("s_waitcnt vmcnt(4)" ::: "memory");

#define RDA(dst_, BUF_, MH_) do { \
    const unsigned short* Ab_ = lds + (BUF_) * 32768 + (MH_) * 8192; \
    _Pragma("unroll") for (int ks = 0; ks < 2; ks++) \
      _Pragma("unroll") for (int fi = 0; fi < 4; fi++) \
        dst_[ks][fi] = *(const bf16x8*)(Ab_ + (wm * 64 + fi * 16 + m16) * 64 + (((ks * 4 + quad) ^ sw) * 8)); \
  } while (0)

#define RDB(BUF_, NH_) do { \
    const unsigned short* Bb_ = lds + (BUF_) * 32768 + 16384 + (NH_) * 8192; \
    _Pragma("unroll") for (int ks = 0; ks < 2; ks++) \
      _Pragma("unroll") for (int gj = 0; gj < 2; gj++) \
        bb[ks][gj] = *(const bf16x8*)(Bb_ + (wn * 32 + gj * 16 + m16) * 64 + (((ks * 4 + quad) ^ sw) * 8)); \
  } while (0)

#define MM(A_, MH_, NH_) \
    _Pragma("unroll") for (int ks = 0; ks < 2; ks++) \
      _Pragma("unroll") for (int fi = 0; fi < 4; fi++) \
        _Pragma("unroll") for (int gj = 0; gj < 2; gj++) \
          acc[MH_][NH_][fi][gj] = __builtin_amdgcn_mfma_f32_16x16x32_bf16( \
              A_[ks][fi], bb[ks][gj], acc[MH_][NH_][fi][gj], 0, 0, 0);

#define PH(RD_, STG_, W_, MM_) do { \
    RD_; \
    STG_; \
    W_ \
    __builtin_amdgcn_s_barrier(); \
    asm volatile("s_waitcnt lgkmcnt(0)" ::: "memory"); \
    __builtin_amdgcn_sched_barrier(0); \
    __builtin_amdgcn_s_setprio(1); \
    MM_ \
    __builtin_amdgcn_s_setprio(0); \
    __builtin_amdgcn_sched_barrier(0); \
    __builtin_amdgcn_s_barrier(); \
  } while (0)

  STAGE(0, 1, 0);
  STAGE(0, 0, 0);
  STAGE(0, 0, 1);
  STAGE(0, 1, 1);
  STAGE(1, 1, 0);
  STAGE(1, 0, 0);
  asm volatile("s_waitcnt vmcnt(4)" ::: "memory");
  __builtin_amdgcn_s_barrier();

  for (int it = 0; it < nit; ++it) {
    int T = it * 2;
    PH(RDA(a0, 0, 0); RDB(0, 0), STAGE(T + 1, 0, 1), , MM(a0, 0, 0));
    PH(RDA(a1, 0, 1),            STAGE(T + 1, 1, 1), , MM(a1, 1, 0));
    PH(RDB(0, 1),                STAGE(T + 2, 1, 0), , MM(a0, 0, 1));
    PH(,                         STAGE(T + 2, 0, 0), VMW, MM(a1, 1, 1));
    PH(RDA(a0, 1, 0); RDB(1, 0), STAGE(T + 2, 0, 1), , MM(a0, 0, 0));
    PH(RDA(a1, 1, 1),            STAGE(T + 2, 1, 1), , MM(a1, 1, 0));
    PH(RDB(1, 1),                STAGE(T + 3, 1, 0), , MM(a0, 0, 1));
    PH(,                         STAGE(T + 3, 0, 0), VMW, MM(a1, 1, 1));
  }

#pragma unroll
  for (int mh = 0; mh < 2; mh++)
#pragma unroll
    for (int nh = 0; nh < 2; nh++)
#pragma unroll
      for (int fi = 0; fi < 4; fi++)
#pragma unroll
        for (int gj = 0; gj < 2; gj++) {
          int rr = row0 + mh * 128 + wm * 64 + fi * 16 + quad * 4;
          int cc = col0 + nh * 128 + wn * 32 + gj * 16 + m16;
#pragma unroll
          for (int r = 0; r < 4; r++)
            C[(size_t)(rr + r) * N + cc] = acc[mh][nh][fi][gj][r];
        }
#undef PH
#undef MM
#undef RDB
#undef RDA
#undef VMW
#undef STAGE
}

// ---------------- bf16 MFMA GEMM: C[M,N] = A[M,K] @ B[N,K]^T ----------------
__global__ __launch_bounds__(256) void gemm_bf16_nt(const unsigned short* __restrict__ A,
                                                    const unsigned short* __restrict__ B,
                                                    float* __restrict__ C,
                                                    int M, int N, int K) {
  __shared__ __align__(16) unsigned short As[128 * 32];
  __shared__ __align__(16) unsigned short Bs[128 * 32];
  int tid = threadIdx.x;
  int wave = tid >> 6;
  int lane = tid & 63;
  int wm = wave >> 1, wn = wave & 1;
  int quad = lane >> 4, m16 = lane & 15;
  int row0 = blockIdx.y * 128, col0 = blockIdx.x * 128;

  floatx4 acc[4][4];
#pragma unroll
  for (int i = 0; i < 4; i++)
#pragma unroll
    for (int j = 0; j < 4; j++) acc[i][j] = (floatx4){0.f, 0.f, 0.f, 0.f};

  int c0 = tid, c1 = tid + 256;
  int r0c = c0 >> 2, q0c = (c0 & 3) * 8;
  int r1c = c1 >> 2, q1c = (c1 & 3) * 8;

  const size_t sK = (size_t)K;
  for (int k0 = 0; k0 < K; k0 += 32) {
    __builtin_amdgcn_global_load_lds(
        (const __attribute__((address_space(1))) unsigned int*)(A + (size_t)(row0 + r0c) * sK + k0 + q0c),
        (__attribute__((address_space(3))) unsigned int*)(As + c0 * 8), 16, 0, 0);
    __builtin_amdgcn_global_load_lds(
        (const __attribute__((address_space(1))) unsigned int*)(A + (size_t)(row0 + r1c) * sK + k0 + q1c),
        (__attribute__((address_space(3))) unsigned int*)(As + c1 * 8), 16, 0, 0);
    __builtin_amdgcn_global_load_lds(
        (const __attribute__((address_space(1))) unsigned int*)(B + (size_t)(col0 + r0c) * sK + k0 + q0c),
        (__attribute__((address_space(3))) unsigned int*)(Bs + c0 * 8), 16, 0, 0);
    __builtin_amdgcn_global_load_lds(
        (const __attribute__((address_space(1))) unsigned int*)(B + (size_t)(col0 + r1c) * sK + k0 + q1c),
        (__attribute__((address_space(3))) unsigned int*)(Bs + c1 * 8), 16, 0, 0);
    __syncthreads();

    bf16x8 af[4], bfr[4];
#pragma unroll
    for (int i = 0; i < 4; i++)
      af[i] = *(const bf16x8*)(As + (wm * 64 + i * 16 + m16) * 32 + quad * 8);
#pragma unroll
    for (int j = 0; j < 4; j++)
      bfr[j] = *(const bf16x8*)(Bs + (wn * 64 + j * 16 + m16) * 32 + quad * 8);
#pragma unroll
    for (int i = 0; i < 4; i++)
#pragma unroll
      for (int j = 0; j < 4; j++)
        acc[i][j] = __builtin_amdgcn_mfma_f32_16x16x32_bf16(af[i], bfr[j], acc[i][j], 0, 0, 0);
    __syncthreads();
  }

#pragma unroll
  for (int i = 0; i < 4; i++) {
#pragma unroll
    for (int j = 0; j < 4; j++) {
      int rr = row0 + wm * 64 + i * 16 + quad * 4;
      int cc = col0 + wn * 64 + j * 16 + m16;
#pragma unroll
      for (int r = 0; r < 4; r++)
        C[(size_t)(rr + r) * N + cc] = acc[i][j][r];
    }
  }
}

// ------- gate GEMM with fused swish*rn epilogue, bf16 output ---------------
__global__ __launch_bounds__(256) void gemm_swish_nt(const unsigned short* __restrict__ A,
                                                     const unsigned short* __restrict__ B,
                                                     const float* __restrict__ rn,
                                                     unsigned short* __restrict__ Hb,
                                                     int M, int N, int K) {
  __shared__ __align__(16) unsigned short As[128 * 32];
  __shared__ __align__(16) unsigned short Bs[128 * 32];
  int tid = threadIdx.x;
  int wave = tid >> 6;
  int lane = tid & 63;
  int wm = wave >> 1, wn = wave & 1;
  int quad = lane >> 4, m16 = lane & 15;
  int row0 = blockIdx.y * 128, col0 = blockIdx.x * 128;

  floatx4 acc[4][4];
#pragma unroll
  for (int i = 0; i < 4; i++)
#pragma unroll
    for (int j = 0; j < 4; j++) acc[i][j] = (floatx4){0.f, 0.f, 0.f, 0.f};

  int c0 = tid, c1 = tid + 256;
  int r0c = c0 >> 2, q0c = (c0 & 3) * 8;
  int r1c = c1 >> 2, q1c = (c1 & 3) * 8;

  const size_t sK = (size_t)K;
  for (int k0 = 0; k0 < K; k0 += 32) {
    __builtin_amdgcn_global_load_lds(
        (const __attribute__((address_space(1))) unsigned int*)(A + (size_t)(row0 + r0c) * sK + k0 + q0c),
        (__attribute__((address_space(3))) unsigned int*)(As + c0 * 8), 16, 0, 0);
    __builtin_amdgcn_global_load_lds(
        (const __attribute__((address_space(1))) unsigned int*)(A + (size_t)(row0 + r1c) * sK + k0 + q1c),
        (__attribute__((address_space(3))) unsigned int*)(As + c1 * 8), 16, 0, 0);
    __builtin_amdgcn_global_load_lds(
        (const __attribute__((address_space(1))) unsigned int*)(B + (size_t)(col0 + r0c) * sK + k0 + q0c),
        (__attribute__((address_space(3))) unsigned int*)(Bs + c0 * 8), 16, 0, 0);
    __builtin_amdgcn_global_load_lds(
        (const __attribute__((address_space(1))) unsigned int*)(B + (size_t)(col0 + r1c) * sK + k0 + q1c),
        (__attribute__((address_space(3))) unsigned int*)(Bs + c1 * 8), 16, 0, 0);
    __syncthreads();

    bf16x8 af[4], bfr[4];
#pragma unroll
    for (int i = 0; i < 4; i++)
      af[i] = *(const bf16x8*)(As + (wm * 64 + i * 16 + m16) * 32 + quad * 8);
#pragma unroll
    for (int j = 0; j < 4; j++)
      bfr[j] = *(const bf16x8*)(Bs + (wn * 64 + j * 16 + m16) * 32 + quad * 8);
#pragma unroll
    for (int i = 0; i < 4; i++)
#pragma unroll
      for (int j = 0; j < 4; j++)
        acc[i][j] = __builtin_amdgcn_mfma_f32_16x16x32_bf16(af[i], bfr[j], acc[i][j], 0, 0, 0);
    __syncthreads();
  }

#pragma unroll
  for (int i = 0; i < 4; i++) {
#pragma unroll
    for (int j = 0; j < 4; j++) {
      int rr = row0 + wm * 64 + i * 16 + quad * 4;
      int cc = col0 + wn * 64 + j * 16 + m16;
#pragma unroll
      for (int r = 0; r < 4; r++) {
        float g = acc[i][j][r];
        float rv = rn[(size_t)(rr + r) * N + cc];
        float hh = g / (1.f + __expf(-g)) * rv;
        Hb[(size_t)(rr + r) * N + cc] = f2bf(hh);
      }
    }
  }
}

// ---------------- alpha: block = 4 t-rows staged in LDS, loop 16 heads ------
__global__ __launch_bounds__(256) void alpha_kernel(const float* __restrict__ x,
                                                    const float* __restrict__ W_alpha,
                                                    const float* __restrict__ b_alpha,
                                                    const float* __restrict__ alpha_base,
                                                    float* __restrict__ a_raw) {
  __shared__ float xs[4][2048];
  int tid = threadIdx.x;
  int t0 = blockIdx.x * 4;
#pragma unroll
  for (int p = 0; p < 8; p++) {
    int idx = tid + p * 256;
    int row = idx >> 9, c4 = idx & 511;
    *(float4*)&xs[row][c4 * 4] = *(const float4*)(x + (size_t)(t0 + row) * DMODEL + c4 * 4);
  }
  __syncthreads();
  int w = tid >> 6, lane = tid & 63;
  int t = t0 + w;
#pragma unroll
  for (int h = 0; h < NHEADS; h++) {
    const float4* wr = (const float4*)(W_alpha + (size_t)h * DMODEL);
    float s = 0.f;
#pragma unroll
    for (int i = lane; i < 512; i += 64) {
      float4 a = *(const float4*)&xs[w][i * 4];
      float4 b = wr[i];
      s += a.x * b.x + a.y * b.y + a.z * b.z + a.w * b.w;
    }
#pragma unroll
    for (int off = 32; off > 0; off >>= 1) s += __shfl_down(s, off);
    if (lane == 0) {
      float sig = 1.f / (1.f + __expf(-(s + b_alpha[h])));
      a_raw[(size_t)h * SQLEN + t] = alpha_base[h] * 8.f * sig;
    }
  }
}

// ---------------- cumsum ----------------------------------------------------
__global__ __launch_bounds__(256) void cumsum_kernel(const float* __restrict__ a_raw,
                                                     float* __restrict__ A) {
  int h = blockIdx.x;
  __shared__ float part[256];
  int tid = threadIdx.x;
  float v[8];
  float s = 0.f;
#pragma unroll
  for (int i = 0; i < 8; i++) {
    v[i] = a_raw[(size_t)h * SQLEN + tid * 8 + i];
    s += v[i];
  }
  part[tid] = s;
  __syncthreads();
  for (int off = 1; off < 256; off <<= 1) {
    float tmp = (tid >= off) ? part[tid - off] : 0.f;
    __syncthreads();
    part[tid] += tmp;
    __syncthreads();
  }
  float run = (tid > 0) ? part[tid - 1] : 0.f;
#pragma unroll
  for (int i = 0; i < 8; i++) {
    run += v[i];
    A[(size_t)h * SQLEN + tid * 8 + i] = run;
  }
}

// ---------------- xPos: emit q,k,v directly as bf16 [h][t][d] ---------------
__global__ __launch_bounds__(256) void xpos_kernel(const float* __restrict__ qkv,
                                                   const float* __restrict__ a_raw,
                                                   const int* __restrict__ offset_p,
                                                   unsigned short* __restrict__ qb,
                                                   unsigned short* __restrict__ kb,
                                                   unsigned short* __restrict__ vb) {
  int idx = blockIdx.x * 256 + threadIdx.x;
  int j = idx & 63;
  int t = (idx >> 6) & 2047;
  int h = idx >> 17;
  float pos = (float)(t + offset_p[0]);
  float freq = exp2f(-(float)j * (13.287712379549449f / 64.f));
  float ang = pos * freq;
  float sn = __sinf(ang), cs = __cosf(ang);
  float zeta = (2.f * (float)j + 51.2f) / 179.2f;
  float lzp = __log2f(zeta) * pos * (1.f / 512.f);
  float sc = exp2f(lzp);
  float sci = exp2f(-lzp);
  const float* row = qkv + (size_t)t * (3 * DMODEL);
  int base = h * DHEAD + j;
  float q1 = row[base], q2 = row[base + 64];
  float k1 = row[DMODEL + base], k2 = row[DMODEL + base + 64];
  float v1 = row[2 * DMODEL + base], v2 = row[2 * DMODEL + base + 64];
  size_t o = ((size_t)h * SQLEN + t) * DHEAD + j;
  qb[o] = f2bf((q1 * cs - q2 * sn) * sc);
  qb[o + 64] = f2bf((q2 * cs + q1 * sn) * sc);
  float km = (1.f - __expf(a_raw[(size_t)h * SQLEN + t])) * sci;
  kb[o] = f2bf((k1 * cs - k2 * sn) * km);
  kb[o + 64] = f2bf((k2 * cs + k1 * sn) * km);
  vb[o] = f2bf(v1);
  vb[o + 64] = f2bf(v2);
}

// ------- transpose kb/vb [h][t][d] -> [h][d][t]; k gets exp(B-A[t]) scale ---
__global__ __launch_bounds__(256) void transpose_kv_kernel(const unsigned short* __restrict__ kb,
                                                           const unsigned short* __restrict__ vb,
                                                           const float* __restrict__ A,
                                                           unsigned short* __restrict__ kT,
                                                           unsigned short* __restrict__ vT) {
  __shared__ __align__(16) unsigned short tile[64][72];
  int h = blockIdx.z >> 1, sel = blockIdx.z & 1;
  int t0 = blockIdx.x * 64, d0 = blockIdx.y * 64;
  int tid = threadIdx.x;
  const unsigned short* src = (sel ? vb : kb) + ((size_t)h * SQLEN + t0) * DHEAD + d0;
  unsigned short* dst = (sel ? vT : kT) + (size_t)h * (DHEAD * SQLEN) + (size_t)d0 * SQLEN + t0;
  float B = A[(size_t)h * SQLEN + SQLEN - 1];
#pragma unroll
  for (int p = 0; p < 2; p++) {
    int c = tid + p * 256;
    int r = c >> 3, off = (c & 7) * 8;
    bf16x8 in = *(const bf16x8*)(src + (size_t)r * DHEAD + off);
    if (!sel) {
      float w = __expf(B - A[(size_t)h * SQLEN + t0 + r]);
      bf16x8 o;
#pragma unroll
      for (int j = 0; j < 8; j++) o[j] = (short)f2bf(bf2f((unsigned short)in[j]) * w);
      *(bf16x8*)&tile[r][off] = o;
    } else {
      *(bf16x8*)&tile[r][off] = in;
    }
  }
  __syncthreads();
#pragma unroll
  for (int p = 0; p < 2; p++) {
    int c = tid + p * 256;
    int dr = c >> 3, toff = (c & 7) * 8;
    bf16x8 o;
#pragma unroll
    for (int j = 0; j < 8; j++) o[j] = (short)tile[toff + j][dr];
    *(bf16x8*)(dst + (size_t)dr * SQLEN + toff) = o;
  }
}

// ---------------- transpose state -> stT bf16 [h][e][d] ---------------------
__global__ __launch_bounds__(256) void transpose_state_kernel(const float* __restrict__ st,
                                                              unsigned short* __restrict__ stT) {
  __shared__ float tile[64][65];
  int h = blockIdx.z, d0 = blockIdx.x * 64, e0 = blockIdx.y * 64;
  int tid = threadIdx.x;
  const float* src = st + (size_t)h * 16384 + (size_t)d0 * DHEAD + e0;
#pragma unroll
  for (int p = 0; p < 4; p++) {
    int idx = tid + p * 256;
    int r = idx >> 4, c = (idx & 15) * 4;
    float4 f = *(const float4*)(src + (size_t)r * DHEAD + c);
    tile[r][c] = f.x; tile[r][c + 1] = f.y; tile[r][c + 2] = f.z; tile[r][c + 3] = f.w;
  }
  __syncthreads();
  unsigned short* dst = stT + (size_t)h * 16384 + (size_t)e0 * DHEAD + d0;
#pragma unroll
  for (int p = 0; p < 2; p++) {
    int idx = tid + p * 256;
    int er = idx >> 3, doff = (idx & 7) * 8;
    bf16x8 o;
#pragma unroll
    for (int j = 0; j < 8; j++) o[j] = (short)f2bf(tile[doff + j][er]);
    *(bf16x8*)(dst + (size_t)er * DHEAD + doff) = o;
  }
}

// ---------------- retention v7: split-j partial blocks + atomic combine -----
// Load imbalance was the bottleneck (occ 8.75%): critical path = 32-tile
// block. Split j-range into chunks of 8 tiles; grid (h, it, jc<=4); partials
// accumulate via fp32 atomicAdd into zeroed R32. Group norm moved to its own
// kernel. exp(Ai-c)*exp(c-Aj) = exp(Ai-Aj) is absolute, so partials sum.
// All exit conditions are block-uniform (no divergent barriers).
__global__ __launch_bounds__(256) void retention_partial(const unsigned short* __restrict__ qb,
                                                         const unsigned short* __restrict__ kb,
                                                         const unsigned short* __restrict__ vT,
                                                         const unsigned short* __restrict__ stT,
                                                         const float* __restrict__ A,
                                                         float* __restrict__ R32) {
  __shared__ __align__(16) unsigned short ks[2][64 * 128];
  __shared__ __align__(16) unsigned short vs[2][128 * 64];
  __shared__ __align__(16) unsigned short Ss[64 * 72];
  int h = blockIdx.x;
  int i0 = blockIdx.y * 64;
  int jc = blockIdx.z;
  int jlo = jc * 512;
  if (jlo > i0) return;                 // uniform
  int jhi = min(i0, jlo + 448);         // last j-tile start in this chunk
  int tid = threadIdx.x;
  int wave = tid >> 6, lane = tid & 63, quad = lane >> 4, m16 = lane & 15;
  const float* Ah = A + (size_t)h * SQLEN;
  float c = Ah[i0];
  int rq = wave * 16 + m16;

  // wave-parallel scan for first non-skipped j-tile (prefix is monotone)
  bool skipl = false;
  if (lane < 32) {
    int j0l = lane * 64;
    if (j0l <= i0) skipl = (c - Ah[j0l + 63] < -87.f);
  }
  unsigned long long smask = __ballot(skipl);
  int j_start = 64 * (int)__builtin_ctzll(~smask);
  int j_begin = max(j_start, jlo);
  bool work = (j_begin <= jhi);         // uniform
  bool crossw = (jc == 0) && (c > -87.f);  // uniform
  if (!work && !crossw) return;

  const unsigned short* qh = qb + ((size_t)h * SQLEN + i0 + rq) * DHEAD;
  bf16x8 qf[4];
#pragma unroll
  for (int dc = 0; dc < 4; dc++)
    qf[dc] = *(const bf16x8*)(qh + dc * 32 + quad * 8);
  float ei = __expf(Ah[i0 + rq] - c);

  floatx4 acc[8];
#pragma unroll
  for (int et = 0; et < 8; et++) acc[et] = (floatx4){0.f, 0.f, 0.f, 0.f};

  const unsigned short* khb = kb + (size_t)h * SQLEN * DHEAD;
  const unsigned short* vhb = vT + (size_t)h * (DHEAD * SQLEN);

#define STAGE_KV(b_, j0_) do { \
    const unsigned short* kh_ = khb + (size_t)(j0_) * DHEAD; \
    const unsigned short* vh_ = vhb + (j0_); \
    _Pragma("unroll") for (int p = 0; p < 4; p++) { \
      int cch = tid + p * 256; \
      int r_ = cch >> 4, kp_ = (cch & 15) ^ (r_ & 7); \
      GLD(kh_ + (size_t)r_ * DHEAD + kp_ * 8, &ks[b_][0] + cch * 8); \
      int e_ = cch >> 3, tp_ = (cch & 7) ^ (e_ & 7); \
      GLD(vh_ + (size_t)e_ * SQLEN + tp_ * 8, &vs[b_][0] + cch * 8); \
    } \
  } while (0)

  if (work) STAGE_KV(0, j_begin);       // latency hides under cross term

  if (crossw) {
    const unsigned short* sp = stT + (size_t)h * 16384;
    float ecr[4];
#pragma unroll
    for (int r = 0; r < 4; r++) ecr[r] = __expf(Ah[i0 + wave * 16 + quad * 4 + r]);
#pragma unroll
    for (int et = 0; et < 8; et++) {
#pragma unroll
      for (int dc = 0; dc < 4; dc++) {
        bf16x8 sf = *(const bf16x8*)(sp + (et * 16 + m16) * DHEAD + dc * 32 + quad * 8);
        acc[et] = __builtin_amdgcn_mfma_f32_16x16x32_bf16(qf[dc], sf, acc[et], 0, 0, 0);
      }
#pragma unroll
      for (int r = 0; r < 4; r++) acc[et][r] *= ecr[r];
    }
  }

  if (work) {
    int cur = 0;
    for (int j0 = j_begin; j0 <= jhi; j0 += 64) {
      int nxt = j0 + 64;
      // decay source issued BEFORE the staging GLDs: loop vmem window after
      // this point is exactly the 8 GLDs (v6 lesson).
      float av = Ah[j0 + lane];
      __builtin_amdgcn_sched_barrier(0);
      if (nxt <= jhi) {
        STAGE_KV(cur ^ 1, nxt);
        asm volatile("s_waitcnt vmcnt(8) lgkmcnt(0)" ::: "memory");
      } else {
        asm volatile("s_waitcnt vmcnt(0) lgkmcnt(0)" ::: "memory");
      }
      __builtin_amdgcn_sched_barrier(0);
      asm volatile("s_barrier" ::: "memory");  // cur landed globally

      float dj = __expf(c - av);

      bool diag = (j0 == i0);
      const unsigned short* ksc = &ks[cur][0];
      const unsigned short* vsc = &vs[cur][0];
#pragma unroll
      for (int jt = 0; jt < 4; jt++) {
        floatx4 s = (floatx4){0.f, 0.f, 0.f, 0.f};
#pragma unroll
        for (int dc = 0; dc < 4; dc++) {
          int rk = jt * 16 + m16;
          bf16x8 kf = *(const bf16x8*)(ksc + rk * 128 + (((dc * 4 + quad) ^ (rk & 7)) * 8));
          s = __builtin_amdgcn_mfma_f32_16x16x32_bf16(kf, qf[dc], s, 0, 0, 0);
        }
        int jb = jt * 16 + quad * 4;
        float d0 = __shfl(dj, jb + 0);
        float d1 = __shfl(dj, jb + 1);
        float d2 = __shfl(dj, jb + 2);
        float d3 = __shfl(dj, jb + 3);
        ushort4 pk;
        pk.x = f2bf((diag && (jb + 0 > rq)) ? 0.f : s[0] * ei * d0);
        pk.y = f2bf((diag && (jb + 1 > rq)) ? 0.f : s[1] * ei * d1);
        pk.z = f2bf((diag && (jb + 2 > rq)) ? 0.f : s[2] * ei * d2);
        pk.w = f2bf((diag && (jb + 3 > rq)) ? 0.f : s[3] * ei * d3);
        *(ushort4*)(Ss + rq * 72 + jb) = pk;
      }

      bf16x8 sfr[2];
#pragma unroll
      for (int kc = 0; kc < 2; kc++)
        sfr[kc] = *(const bf16x8*)(Ss + rq * 72 + kc * 32 + quad * 8);
#pragma unroll
      for (int et = 0; et < 8; et++) {
#pragma unroll
        for (int kc = 0; kc < 2; kc++) {
          int e = et * 16 + m16;
          bf16x8 vf = *(const bf16x8*)(vsc + e * 64 + (((kc * 4 + quad) ^ (e & 7)) * 8));
          acc[et] = __builtin_amdgcn_mfma_f32_16x16x32_bf16(sfr[kc], vf, acc[et], 0, 0, 0);
        }
      }
      asm volatile("s_barrier" ::: "memory");
      cur ^= 1;
    }
  }
#undef STAGE_KV

  // atomic partial accumulation into R32
#pragma unroll
  for (int r = 0; r < 4; r++) {
    int row = i0 + wave * 16 + quad * 4 + r;
    size_t o = (size_t)row * DMODEL + h * DHEAD;
#pragma unroll
    for (int et = 0; et < 8; et++)
      atomicAdd(&R32[o + et * 16 + m16], acc[et][r]);
  }
}

// ---------------- group norm over R32 -> rn fp32 + rnb bf16 -----------------
__global__ __launch_bounds__(256) void gn_kernel(const float* __restrict__ R32,
                                                 const float* __restrict__ gn_w,
                                                 const float* __restrict__ gn_b,
                                                 float* __restrict__ rn,
                                                 unsigned short* __restrict__ rnb) {
  int row = blockIdx.x;
  int tid = threadIdx.x;
  const float* src = R32 + (size_t)row * DMODEL + tid * 8;
  float4 a = *(const float4*)src;
  float4 b = *(const float4*)(src + 4);
  float s = a.x + a.y + a.z + a.w + b.x + b.y + b.z + b.w;
  float ss = a.x * a.x + a.y * a.y + a.z * a.z + a.w * a.w +
             b.x * b.x + b.y * b.y + b.z * b.z + b.w * b.w;
  // reduce across the 16 threads of this head (lanes share a wave; bits 0-3)
#pragma unroll
  for (int off = 8; off > 0; off >>= 1) {
    s += __shfl_xor(s, off);
    ss += __shfl_xor(ss, off);
  }
  float mu = s * (1.f / 128.f);
  float var = ss * (1.f / 128.f) - mu * mu;
  float inv = rsqrtf(var + 1e-5f);
  int col0 = tid * 8;
  const float* wp = gn_w + col0;
  const float* bp = gn_b + col0;
  float v[8] = {a.x, a.y, a.z, a.w, b.x, b.y, b.z, b.w};
  float o[8];
  ushort4 ob[2];
#pragma unroll
  for (int k = 0; k < 8; k++) {
    o[k] = (v[k] - mu) * inv * wp[k] + bp[k];
    ((unsigned short*)ob)[k] = f2bf(o[k]);
  }
  float* rp = rn + (size_t)row * DMODEL + col0;
  *(float4*)rp = (float4){o[0], o[1], o[2], o[3]};
  *(float4*)(rp + 4) = (float4){o[4], o[5], o[6], o[7]};
  *(ushort4*)(rnb + (size_t)row * DMODEL + col0) = ob[0];
  *(ushort4*)(rnb + (size_t)row * DMODEL + col0 + 4) = ob[1];
}

// -------- new_state GEMM: P[h,chunk] = kT_s[:,krange] @ vT[:,krange]^T ------
__global__ __launch_bounds__(256) void state_gemm(const unsigned short* __restrict__ kT,
                                                  const unsigned short* __restrict__ vT,
                                                  float* __restrict__ P) {
  __shared__ __align__(16) unsigned short As[128 * 32];
  __shared__ __align__(16) unsigned short Bs[128 * 32];
  int chunk = blockIdx.x, h = blockIdx.y;
  int tid = threadIdx.x;
  int wave = tid >> 6, lane = tid & 63;
  int wm = wave >> 1, wn = wave & 1;
  int quad = lane >> 4, m16 = lane & 15;
  const unsigned short* Ab = kT + (size_t)h * (DHEAD * SQLEN);
  const unsigned short* Bb = vT + (size_t)h * (DHEAD * SQLEN);

  floatx4 acc[4][4];
#pragma unroll
  for (int i = 0; i < 4; i++)
#pragma unroll
    for (int j = 0; j < 4; j++) acc[i][j] = (floatx4){0.f, 0.f, 0.f, 0.f};

  int c0 = tid, c1 = tid + 256;
  int r0c = c0 >> 2, q0c = (c0 & 3) * 8;
  int r1c = c1 >> 2, q1c = (c1 & 3) * 8;

  for (int k0 = chunk * 256; k0 < chunk * 256 + 256; k0 += 32) {
    __builtin_amdgcn_global_load_lds(
        (const __attribute__((address_space(1))) unsigned int*)(Ab + (size_t)r0c * SQLEN + k0 + q0c),
        (__attribute__((address_space(3))) unsigned int*)(As + c0 * 8), 16, 0, 0);
    __builtin_amdgcn_global_load_lds(
        (const __attribute__((address_space(1))) unsigned int*)(Ab + (size_t)r1c * SQLEN + k0 + q1c),
        (__attribute__((address_space(3))) unsigned int*)(As + c1 * 8), 16, 0, 0);
    __builtin_amdgcn_global_load_lds(
        (const __attribute__((address_space(1))) unsigned int*)(Bb + (size_t)r0c * SQLEN + k0 + q0c),
        (__attribute__((address_space(3))) unsigned int*)(Bs + c0 * 8), 16, 0, 0);
    __builtin_amdgcn_global_load_lds(
        (const __attribute__((address_space(1))) unsigned int*)(Bb + (size_t)r1c * SQLEN + k0 + q1c),
        (__attribute__((address_space(3))) unsigned int*)(Bs + c1 * 8), 16, 0, 0);
    __syncthreads();

    bf16x8 af[4], bfr[4];
#pragma unroll
    for (int i = 0; i < 4; i++)
      af[i] = *(const bf16x8*)(As + (wm * 64 + i * 16 + m16) * 32 + quad * 8);
#pragma unroll
    for (int j = 0; j < 4; j++)
      bfr[j] = *(const bf16x8*)(Bs + (wn * 64 + j * 16 + m16) * 32 + quad * 8);
#pragma unroll
    for (int i = 0; i < 4; i++)
#pragma unroll
      for (int j = 0; j < 4; j++)
        acc[i][j] = __builtin_amdgcn_mfma_f32_16x16x32_bf16(af[i], bfr[j], acc[i][j], 0, 0, 0);
    __syncthreads();
  }

  float* Pp = P + (size_t)(h * 8 + chunk) * 16384;
#pragma unroll
  for (int i = 0; i < 4; i++)
#pragma unroll
    for (int j = 0; j < 4; j++) {
      int rr = wm * 64 + i * 16 + quad * 4;
      int cc = wn * 64 + j * 16 + m16;
#pragma unroll
      for (int r = 0; r < 4; r++)
        Pp[(size_t)(rr + r) * DHEAD + cc] = acc[i][j][r];
    }
}

__global__ __launch_bounds__(256) void state_combine(const float* __restrict__ P,
                                                     const float* __restrict__ state,
                                                     const float* __restrict__ A,
                                                     float* __restrict__ out_state) {
  int idx = blockIdx.x * 256 + threadIdx.x;
  int h = idx >> 14;
  int de = idx & 16383;
  float B = A[(size_t)h * SQLEN + SQLEN - 1];
  float s = __expf(B) * state[idx];
#pragma unroll
  for (int c = 0; c < 8; c++) s += P[(size_t)(h * 8 + c) * 16384 + de];
  out_state[idx] = s;
}

extern "C" void kernel_launch(void* const* d_in, const int* in_sizes, int n_in,
                              void* d_out, int out_size, void* d_ws, size_t ws_size,
                              hipStream_t stream) {
  const float* x = (const float*)d_in[0];
  const float* state = (const float*)d_in[1];
  const float* W_qkv = (const float*)d_in[2];
  const float* W_alpha = (const float*)d_in[3];
  const float* b_alpha = (const float*)d_in[4];
  const float* alpha_base = (const float*)d_in[5];
  const float* gn_w = (const float*)d_in[6];
  const float* gn_b = (const float*)d_in[7];
  const float* W_out = (const float*)d_in[8];
  const float* W_gate = (const float*)d_in[9];
  const int* offset = (const int*)d_in[10];

  float* ws = (float*)d_ws;
  float* qkv = ws;                      // [0,12582912) alive gemm -> xpos
  float* R32 = ws + 4194304;            // [4194304,8388608) after xpos (over qkv)
  float* P   = ws + 8388608;            // [8388608,10485760) after retention
  float* rn  = ws + 29360128;
  float* araw = ws + 33554432;
  float* Acum = ws + 33587200;

  unsigned short* xb    = (unsigned short*)(ws + 12582912);
  unsigned short* Wqkvb = (unsigned short*)(ws + 16777216);
  unsigned short* qb    = (unsigned short*)(ws + 12582912);
  unsigned short* kb    = (unsigned short*)(ws + 14680064);
  unsigned short* vb    = (unsigned short*)(ws + 16777216);
  unsigned short* kT_s  = (unsigned short*)(ws + 18874368);
  unsigned short* vT_b  = (unsigned short*)(ws + 20971520);
  unsigned short* stT_b = (unsigned short*)(ws + 23068672);
  unsigned short* rnb   = (unsigned short*)(ws + 25165824);
  unsigned short* Wgateb = (unsigned short*)(ws + 14680064);
  unsigned short* Woutb  = (unsigned short*)(ws + 16777216);
  unsigned short* Hb     = (unsigned short*)(ws + 18874368);

  float* out = (float*)d_out;
  float* out_state = out + 4194304;

  dim3 blk(256);
  f2b2_kernel<<<dim3(16384), blk, 0, stream>>>((const float4*)x, (ushort4*)xb,
                                               (const float4*)W_qkv, (ushort4*)Wqkvb, 4096);
  gemm256_nt<<<dim3(24, 8), dim3(512), 0, stream>>>(xb, Wqkvb, qkv, 2048, 6144, 2048);

  alpha_kernel<<<dim3(512), blk, 0, stream>>>(x, W_alpha, b_alpha, alpha_base, araw);
  cumsum_kernel<<<dim3(16), blk, 0, stream>>>(araw, Acum);
  xpos_kernel<<<dim3(8192), blk, 0, stream>>>(qkv, araw, offset, qb, kb, vb);
  // qkv dead; zero the partial-accumulation buffer (overlays qkv region)
  zero_kernel<<<dim3(4096), blk, 0, stream>>>((float4*)R32);
  transpose_kv_kernel<<<dim3(32, 2, 32), blk, 0, stream>>>(kb, vb, Acum, kT_s, vT_b);
  transpose_state_kernel<<<dim3(2, 2, 16), blk, 0, stream>>>(state, stT_b);

  retention_partial<<<dim3(16, 32, 4), blk, 0, stream>>>(qb, kb, vT_b, stT_b, Acum, R32);
  gn_kernel<<<dim3(2048), blk, 0, stream>>>(R32, gn_w, gn_b, rn, rnb);

  state_gemm<<<dim3(8, 16), blk, 0, stream>>>(kT_s, vT_b, P);
  state_combine<<<dim3(1024), blk, 0, stream>>>(P, state, Acum, out_state);

  f2b2_kernel<<<dim3(8192), blk, 0, stream>>>((const float4*)W_gate, (ushort4*)Wgateb,
                                              (const float4*)W_out, (ushort4*)Woutb, 4096);
  gemm_swish_nt<<<dim3(16, 16), blk, 0, stream>>>(rnb, Wgateb, rn, Hb, 2048, 2048, 2048);
  gemm_bf16_nt<<<dim3(16, 16), blk, 0, stream>>>(Hb, Woutb, out, 2048, 2048, 2048);
}

// Round 9
// 423.417 us; speedup vs baseline: 1.0153x; 1.0153x over previous
//
#include <hip/hip_runtime.h>
#include <cstddef>

#define SQLEN 2048
#define DMODEL 2048
#define NHEADS 16
#define DHEAD 128

typedef __attribute__((ext_vector_type(8))) short bf16x8;
typedef __attribute__((ext_vector_type(4))) float floatx4;

__device__ __forceinline__ unsigned short f2bf(float f) {
  union { float f; unsigned u; } c; c.f = f;
  unsigned u = c.u;
  unsigned r = u + 0x7fffu + ((u >> 16) & 1u);
  return (unsigned short)(r >> 16);
}
__device__ __forceinline__ float bf2f(unsigned short s) {
  union { unsigned u; float f; } c; c.u = ((unsigned)s) << 16;
  return c.f;
}

// ---------------- fp32 -> bf16 convert (vectorized) -------------------------
__global__ __launch_bounds__(256) void f2b_kernel(const float4* __restrict__ in,
                                                  ushort4* __restrict__ out) {
  int i = blockIdx.x * 256 + threadIdx.x;
  float4 v = in[i];
  ushort4 o;
  o.x = f2bf(v.x); o.y = f2bf(v.y); o.z = f2bf(v.z); o.w = f2bf(v.w);
  out[i] = o;
}

// two-array variant (two tensors in one launch)
__global__ __launch_bounds__(256) void f2b2_kernel(const float4* __restrict__ in0,
                                                   ushort4* __restrict__ out0,
                                                   const float4* __restrict__ in1,
                                                   ushort4* __restrict__ out1,
                                                   int half_blocks) {
  int b = blockIdx.x;
  const float4* in = (b < half_blocks) ? in0 : in1;
  ushort4* out = (b < half_blocks) ? out0 : out1;
  int i = (b < half_blocks ? b : b - half_blocks) * 256 + threadIdx.x;
  float4 v = in[i];
  ushort4 o;
  o.x = f2bf(v.x); o.y = f2bf(v.y); o.z = f2bf(v.z); o.w = f2bf(v.w);
  out[i] = o;
}

// =================== 256x256 8-phase bf16 GEMM (C = A @ B^T) ================
#define GLD(srcp, dstp) __builtin_amdgcn_global_load_lds( \
    (const __attribute__((address_space(1))) unsigned int*)(srcp), \
    (__attribute__((address_space(3))) unsigned int*)(dstp), 16, 0, 0)

__global__ __launch_bounds__(512, 2) void gemm256_nt(const unsigned short* __restrict__ A,
                                                     const unsigned short* __restrict__ B,
                                                     float* __restrict__ C,
                                                     int M, int N, int K) {
  __shared__ __align__(16) unsigned short lds[65536];  // 128 KiB
  int tid = threadIdx.x;
  int wave = tid >> 6, lane = tid & 63;
  int wm = wave >> 2, wn = wave & 3;            // 2 x 4 wave grid
  int quad = lane >> 4, m16 = lane & 15;
  int sw = m16 & 7;

  int nTN = gridDim.x;
  int lin = blockIdx.y * nTN + blockIdx.x;
  int nwg = gridDim.x * gridDim.y;
  int swzb = (nwg & 7) == 0 ? ((lin & 7) * (nwg >> 3) + (lin >> 3)) : lin;
  int row0 = (swzb / nTN) * 256, col0 = (swzb % nTN) * 256;

  const int nkt = K >> 6;    // K-tiles of 64
  const int nit = K >> 7;    // loop iters (2 tiles each)

  int srow = tid >> 3;
  int scol8 = (((tid & 7) ^ ((tid >> 3) & 7)) * 8);  // pre-swizzled global col

  bf16x8 a0[2][4], a1[2][4], bb[2][2];
  floatx4 acc[2][2][4][2];
#pragma unroll
  for (int a = 0; a < 2; a++)
#pragma unroll
    for (int b = 0; b < 2; b++)
#pragma unroll
      for (int c = 0; c < 4; c++)
#pragma unroll
        for (int d = 0; d < 2; d++) acc[a][b][c][d] = (floatx4){0.f, 0.f, 0.f, 0.f};

#define STAGE(t_, ab_, h_) do { \
    int t2_ = (t_); if (t2_ >= nkt) t2_ -= nkt; \
    const unsigned short* gp_ = (ab_) ? B : A; \
    int rb_ = ((ab_) ? col0 : row0) + (h_) * 128 + srow; \
    int kk_ = t2_ * 64 + scol8; \
    unsigned bs_ = ((unsigned)((t_) & 1)) * 32768u + (ab_) * 16384u + (h_) * 8192u; \
    GLD(gp_ + (size_t)rb_ * K + kk_, lds + bs_ + tid * 8); \
    GLD(gp_ + (size_t)(rb_ + 64) * K + kk_, lds + bs_ + 4096 + tid * 8); \
  } while (0)

#define VMW asm volatile("s_waitcnt vmcnt(4)" ::: "memory");

#define RDA(dst_, BUF_, MH_) do { \
    const unsigned short* Ab_ = lds + (BUF_) * 32768 + (MH_) * 8192; \
    _Pragma("unroll") for (int ks = 0; ks < 2; ks++) \
      _Pragma("unroll") for (int fi = 0; fi < 4; fi++) \
        dst_[ks][fi] = *(const bf16x8*)(Ab_ + (wm * 64 + fi * 16 + m16) * 64 + (((ks * 4 + quad) ^ sw) * 8)); \
  } while (0)

#define RDB(BUF_, NH_) do { \
    const unsigned short* Bb_ = lds + (BUF_) * 32768 + 16384 + (NH_) * 8192; \
    _Pragma("unroll") for (int ks = 0; ks < 2; ks++) \
      _Pragma("unroll") for (int gj = 0; gj < 2; gj++) \
        bb[ks][gj] = *(const bf16x8*)(Bb_ + (wn * 32 + gj * 16 + m16) * 64 + (((ks * 4 + quad) ^ sw) * 8)); \
  } while (0)

#define MM(A_, MH_, NH_) \
    _Pragma("unroll") for (int ks = 0; ks < 2; ks++) \
      _Pragma("unroll") for (int fi = 0; fi < 4; fi++) \
        _Pragma("unroll") for (int gj = 0; gj < 2; gj++) \
          acc[MH_][NH_][fi][gj] = __builtin_amdgcn_mfma_f32_16x16x32_bf16( \
              A_[ks][fi], bb[ks][gj], acc[MH_][NH_][fi][gj], 0, 0, 0);

#define PH(RD_, STG_, W_, MM_) do { \
    RD_; \
    STG_; \
    W_ \
    __builtin_amdgcn_s_barrier(); \
    asm volatile("s_waitcnt lgkmcnt(0)" ::: "memory"); \
    __builtin_amdgcn_sched_barrier(0); \
    __builtin_amdgcn_s_setprio(1); \
    MM_ \
    __builtin_amdgcn_s_setprio(0); \
    __builtin_amdgcn_sched_barrier(0); \
    __builtin_amdgcn_s_barrier(); \
  } while (0)

  STAGE(0, 1, 0);
  STAGE(0, 0, 0);
  STAGE(0, 0, 1);
  STAGE(0, 1, 1);
  STAGE(1, 1, 0);
  STAGE(1, 0, 0);
  asm volatile("s_waitcnt vmcnt(4)" ::: "memory");
  __builtin_amdgcn_s_barrier();

  for (int it = 0; it < nit; ++it) {
    int T = it * 2;
    PH(RDA(a0, 0, 0); RDB(0, 0), STAGE(T + 1, 0, 1), , MM(a0, 0, 0));
    PH(RDA(a1, 0, 1),            STAGE(T + 1, 1, 1), , MM(a1, 1, 0));
    PH(RDB(0, 1),                STAGE(T + 2, 1, 0), , MM(a0, 0, 1));
    PH(,                         STAGE(T + 2, 0, 0), VMW, MM(a1, 1, 1));
    PH(RDA(a0, 1, 0); RDB(1, 0), STAGE(T + 2, 0, 1), , MM(a0, 0, 0));
    PH(RDA(a1, 1, 1),            STAGE(T + 2, 1, 1), , MM(a1, 1, 0));
    PH(RDB(1, 1),                STAGE(T + 3, 1, 0), , MM(a0, 0, 1));
    PH(,                         STAGE(T + 3, 0, 0), VMW, MM(a1, 1, 1));
  }

#pragma unroll
  for (int mh = 0; mh < 2; mh++)
#pragma unroll
    for (int nh = 0; nh < 2; nh++)
#pragma unroll
      for (int fi = 0; fi < 4; fi++)
#pragma unroll
        for (int gj = 0; gj < 2; gj++) {
          int rr = row0 + mh * 128 + wm * 64 + fi * 16 + quad * 4;
          int cc = col0 + nh * 128 + wn * 32 + gj * 16 + m16;
#pragma unroll
          for (int r = 0; r < 4; r++)
            C[(size_t)(rr + r) * N + cc] = acc[mh][nh][fi][gj][r];
        }
#undef PH
#undef MM
#undef RDB
#undef RDA
#undef VMW
#undef STAGE
}

// ---------------- bf16 MFMA GEMM: C[M,N] = A[M,K] @ B[N,K]^T ----------------
__global__ __launch_bounds__(256) void gemm_bf16_nt(const unsigned short* __restrict__ A,
                                                    const unsigned short* __restrict__ B,
                                                    float* __restrict__ C,
                                                    int M, int N, int K) {
  __shared__ __align__(16) unsigned short As[128 * 32];
  __shared__ __align__(16) unsigned short Bs[128 * 32];
  int tid = threadIdx.x;
  int wave = tid >> 6;
  int lane = tid & 63;
  int wm = wave >> 1, wn = wave & 1;
  int quad = lane >> 4, m16 = lane & 15;
  int row0 = blockIdx.y * 128, col0 = blockIdx.x * 128;

  floatx4 acc[4][4];
#pragma unroll
  for (int i = 0; i < 4; i++)
#pragma unroll
    for (int j = 0; j < 4; j++) acc[i][j] = (floatx4){0.f, 0.f, 0.f, 0.f};

  int c0 = tid, c1 = tid + 256;
  int r0c = c0 >> 2, q0c = (c0 & 3) * 8;
  int r1c = c1 >> 2, q1c = (c1 & 3) * 8;

  const size_t sK = (size_t)K;
  for (int k0 = 0; k0 < K; k0 += 32) {
    __builtin_amdgcn_global_load_lds(
        (const __attribute__((address_space(1))) unsigned int*)(A + (size_t)(row0 + r0c) * sK + k0 + q0c),
        (__attribute__((address_space(3))) unsigned int*)(As + c0 * 8), 16, 0, 0);
    __builtin_amdgcn_global_load_lds(
        (const __attribute__((address_space(1))) unsigned int*)(A + (size_t)(row0 + r1c) * sK + k0 + q1c),
        (__attribute__((address_space(3))) unsigned int*)(As + c1 * 8), 16, 0, 0);
    __builtin_amdgcn_global_load_lds(
        (const __attribute__((address_space(1))) unsigned int*)(B + (size_t)(col0 + r0c) * sK + k0 + q0c),
        (__attribute__((address_space(3))) unsigned int*)(Bs + c0 * 8), 16, 0, 0);
    __builtin_amdgcn_global_load_lds(
        (const __attribute__((address_space(1))) unsigned int*)(B + (size_t)(col0 + r1c) * sK + k0 + q1c),
        (__attribute__((address_space(3))) unsigned int*)(Bs + c1 * 8), 16, 0, 0);
    __syncthreads();

    bf16x8 af[4], bfr[4];
#pragma unroll
    for (int i = 0; i < 4; i++)
      af[i] = *(const bf16x8*)(As + (wm * 64 + i * 16 + m16) * 32 + quad * 8);
#pragma unroll
    for (int j = 0; j < 4; j++)
      bfr[j] = *(const bf16x8*)(Bs + (wn * 64 + j * 16 + m16) * 32 + quad * 8);
#pragma unroll
    for (int i = 0; i < 4; i++)
#pragma unroll
      for (int j = 0; j < 4; j++)
        acc[i][j] = __builtin_amdgcn_mfma_f32_16x16x32_bf16(af[i], bfr[j], acc[i][j], 0, 0, 0);
    __syncthreads();
  }

#pragma unroll
  for (int i = 0; i < 4; i++) {
#pragma unroll
    for (int j = 0; j < 4; j++) {
      int rr = row0 + wm * 64 + i * 16 + quad * 4;
      int cc = col0 + wn * 64 + j * 16 + m16;
#pragma unroll
      for (int r = 0; r < 4; r++)
        C[(size_t)(rr + r) * N + cc] = acc[i][j][r];
    }
  }
}

// ------- gate GEMM with fused swish*rn epilogue, bf16 output ---------------
__global__ __launch_bounds__(256) void gemm_swish_nt(const unsigned short* __restrict__ A,
                                                     const unsigned short* __restrict__ B,
                                                     const float* __restrict__ rn,
                                                     unsigned short* __restrict__ Hb,
                                                     int M, int N, int K) {
  __shared__ __align__(16) unsigned short As[128 * 32];
  __shared__ __align__(16) unsigned short Bs[128 * 32];
  int tid = threadIdx.x;
  int wave = tid >> 6;
  int lane = tid & 63;
  int wm = wave >> 1, wn = wave & 1;
  int quad = lane >> 4, m16 = lane & 15;
  int row0 = blockIdx.y * 128, col0 = blockIdx.x * 128;

  floatx4 acc[4][4];
#pragma unroll
  for (int i = 0; i < 4; i++)
#pragma unroll
    for (int j = 0; j < 4; j++) acc[i][j] = (floatx4){0.f, 0.f, 0.f, 0.f};

  int c0 = tid, c1 = tid + 256;
  int r0c = c0 >> 2, q0c = (c0 & 3) * 8;
  int r1c = c1 >> 2, q1c = (c1 & 3) * 8;

  const size_t sK = (size_t)K;
  for (int k0 = 0; k0 < K; k0 += 32) {
    __builtin_amdgcn_global_load_lds(
        (const __attribute__((address_space(1))) unsigned int*)(A + (size_t)(row0 + r0c) * sK + k0 + q0c),
        (__attribute__((address_space(3))) unsigned int*)(As + c0 * 8), 16, 0, 0);
    __builtin_amdgcn_global_load_lds(
        (const __attribute__((address_space(1))) unsigned int*)(A + (size_t)(row0 + r1c) * sK + k0 + q1c),
        (__attribute__((address_space(3))) unsigned int*)(As + c1 * 8), 16, 0, 0);
    __builtin_amdgcn_global_load_lds(
        (const __attribute__((address_space(1))) unsigned int*)(B + (size_t)(col0 + r0c) * sK + k0 + q0c),
        (__attribute__((address_space(3))) unsigned int*)(Bs + c0 * 8), 16, 0, 0);
    __builtin_amdgcn_global_load_lds(
        (const __attribute__((address_space(1))) unsigned int*)(B + (size_t)(col0 + r1c) * sK + k0 + q1c),
        (__attribute__((address_space(3))) unsigned int*)(Bs + c1 * 8), 16, 0, 0);
    __syncthreads();

    bf16x8 af[4], bfr[4];
#pragma unroll
    for (int i = 0; i < 4; i++)
      af[i] = *(const bf16x8*)(As + (wm * 64 + i * 16 + m16) * 32 + quad * 8);
#pragma unroll
    for (int j = 0; j < 4; j++)
      bfr[j] = *(const bf16x8*)(Bs + (wn * 64 + j * 16 + m16) * 32 + quad * 8);
#pragma unroll
    for (int i = 0; i < 4; i++)
#pragma unroll
      for (int j = 0; j < 4; j++)
        acc[i][j] = __builtin_amdgcn_mfma_f32_16x16x32_bf16(af[i], bfr[j], acc[i][j], 0, 0, 0);
    __syncthreads();
  }

#pragma unroll
  for (int i = 0; i < 4; i++) {
#pragma unroll
    for (int j = 0; j < 4; j++) {
      int rr = row0 + wm * 64 + i * 16 + quad * 4;
      int cc = col0 + wn * 64 + j * 16 + m16;
#pragma unroll
      for (int r = 0; r < 4; r++) {
        float g = acc[i][j][r];
        float rv = rn[(size_t)(rr + r) * N + cc];
        float hh = g / (1.f + __expf(-g)) * rv;
        Hb[(size_t)(rr + r) * N + cc] = f2bf(hh);
      }
    }
  }
}

// ---------------- alpha: block = 4 t-rows staged in LDS, loop 16 heads ------
__global__ __launch_bounds__(256) void alpha_kernel(const float* __restrict__ x,
                                                    const float* __restrict__ W_alpha,
                                                    const float* __restrict__ b_alpha,
                                                    const float* __restrict__ alpha_base,
                                                    float* __restrict__ a_raw) {
  __shared__ float xs[4][2048];
  int tid = threadIdx.x;
  int t0 = blockIdx.x * 4;
#pragma unroll
  for (int p = 0; p < 8; p++) {
    int idx = tid + p * 256;
    int row = idx >> 9, c4 = idx & 511;
    *(float4*)&xs[row][c4 * 4] = *(const float4*)(x + (size_t)(t0 + row) * DMODEL + c4 * 4);
  }
  __syncthreads();
  int w = tid >> 6, lane = tid & 63;
  int t = t0 + w;
#pragma unroll
  for (int h = 0; h < NHEADS; h++) {
    const float4* wr = (const float4*)(W_alpha + (size_t)h * DMODEL);
    float s = 0.f;
#pragma unroll
    for (int i = lane; i < 512; i += 64) {
      float4 a = *(const float4*)&xs[w][i * 4];
      float4 b = wr[i];
      s += a.x * b.x + a.y * b.y + a.z * b.z + a.w * b.w;
    }
#pragma unroll
    for (int off = 32; off > 0; off >>= 1) s += __shfl_down(s, off);
    if (lane == 0) {
      float sig = 1.f / (1.f + __expf(-(s + b_alpha[h])));
      a_raw[(size_t)h * SQLEN + t] = alpha_base[h] * 8.f * sig;
    }
  }
}

// ---------------- cumsum ----------------------------------------------------
__global__ __launch_bounds__(256) void cumsum_kernel(const float* __restrict__ a_raw,
                                                     float* __restrict__ A) {
  int h = blockIdx.x;
  __shared__ float part[256];
  int tid = threadIdx.x;
  float v[8];
  float s = 0.f;
#pragma unroll
  for (int i = 0; i < 8; i++) {
    v[i] = a_raw[(size_t)h * SQLEN + tid * 8 + i];
    s += v[i];
  }
  part[tid] = s;
  __syncthreads();
  for (int off = 1; off < 256; off <<= 1) {
    float tmp = (tid >= off) ? part[tid - off] : 0.f;
    __syncthreads();
    part[tid] += tmp;
    __syncthreads();
  }
  float run = (tid > 0) ? part[tid - 1] : 0.f;
#pragma unroll
  for (int i = 0; i < 8; i++) {
    run += v[i];
    A[(size_t)h * SQLEN + tid * 8 + i] = run;
  }
}

// ---------------- xPos: emit q,k,v directly as bf16 [h][t][d] ---------------
__global__ __launch_bounds__(256) void xpos_kernel(const float* __restrict__ qkv,
                                                   const float* __restrict__ a_raw,
                                                   const int* __restrict__ offset_p,
                                                   unsigned short* __restrict__ qb,
                                                   unsigned short* __restrict__ kb,
                                                   unsigned short* __restrict__ vb) {
  int idx = blockIdx.x * 256 + threadIdx.x;
  int j = idx & 63;
  int t = (idx >> 6) & 2047;
  int h = idx >> 17;
  float pos = (float)(t + offset_p[0]);
  float freq = exp2f(-(float)j * (13.287712379549449f / 64.f));
  float ang = pos * freq;
  float sn = __sinf(ang), cs = __cosf(ang);
  float zeta = (2.f * (float)j + 51.2f) / 179.2f;
  float lzp = __log2f(zeta) * pos * (1.f / 512.f);
  float sc = exp2f(lzp);
  float sci = exp2f(-lzp);
  const float* row = qkv + (size_t)t * (3 * DMODEL);
  int base = h * DHEAD + j;
  float q1 = row[base], q2 = row[base + 64];
  float k1 = row[DMODEL + base], k2 = row[DMODEL + base + 64];
  float v1 = row[2 * DMODEL + base], v2 = row[2 * DMODEL + base + 64];
  size_t o = ((size_t)h * SQLEN + t) * DHEAD + j;
  qb[o] = f2bf((q1 * cs - q2 * sn) * sc);
  qb[o + 64] = f2bf((q2 * cs + q1 * sn) * sc);
  float km = (1.f - __expf(a_raw[(size_t)h * SQLEN + t])) * sci;
  kb[o] = f2bf((k1 * cs - k2 * sn) * km);
  kb[o + 64] = f2bf((k2 * cs + k1 * sn) * km);
  vb[o] = f2bf(v1);
  vb[o + 64] = f2bf(v2);
}

// ------- transpose kb/vb [h][t][d] -> [h][d][t]; k gets exp(B-A[t]) scale ---
__global__ __launch_bounds__(256) void transpose_kv_kernel(const unsigned short* __restrict__ kb,
                                                           const unsigned short* __restrict__ vb,
                                                           const float* __restrict__ A,
                                                           unsigned short* __restrict__ kT,
                                                           unsigned short* __restrict__ vT) {
  __shared__ __align__(16) unsigned short tile[64][72];
  int h = blockIdx.z >> 1, sel = blockIdx.z & 1;
  int t0 = blockIdx.x * 64, d0 = blockIdx.y * 64;
  int tid = threadIdx.x;
  const unsigned short* src = (sel ? vb : kb) + ((size_t)h * SQLEN + t0) * DHEAD + d0;
  unsigned short* dst = (sel ? vT : kT) + (size_t)h * (DHEAD * SQLEN) + (size_t)d0 * SQLEN + t0;
  float B = A[(size_t)h * SQLEN + SQLEN - 1];
#pragma unroll
  for (int p = 0; p < 2; p++) {
    int c = tid + p * 256;
    int r = c >> 3, off = (c & 7) * 8;
    bf16x8 in = *(const bf16x8*)(src + (size_t)r * DHEAD + off);
    if (!sel) {
      float w = __expf(B - A[(size_t)h * SQLEN + t0 + r]);
      bf16x8 o;
#pragma unroll
      for (int j = 0; j < 8; j++) o[j] = (short)f2bf(bf2f((unsigned short)in[j]) * w);
      *(bf16x8*)&tile[r][off] = o;
    } else {
      *(bf16x8*)&tile[r][off] = in;
    }
  }
  __syncthreads();
#pragma unroll
  for (int p = 0; p < 2; p++) {
    int c = tid + p * 256;
    int dr = c >> 3, toff = (c & 7) * 8;
    bf16x8 o;
#pragma unroll
    for (int j = 0; j < 8; j++) o[j] = (short)tile[toff + j][dr];
    *(bf16x8*)(dst + (size_t)dr * SQLEN + toff) = o;
  }
}

// ---------------- transpose state -> stT bf16 [h][e][d] ---------------------
__global__ __launch_bounds__(256) void transpose_state_kernel(const float* __restrict__ st,
                                                              unsigned short* __restrict__ stT) {
  __shared__ float tile[64][65];
  int h = blockIdx.z, d0 = blockIdx.x * 64, e0 = blockIdx.y * 64;
  int tid = threadIdx.x;
  const float* src = st + (size_t)h * 16384 + (size_t)d0 * DHEAD + e0;
#pragma unroll
  for (int p = 0; p < 4; p++) {
    int idx = tid + p * 256;
    int r = idx >> 4, c = (idx & 15) * 4;
    float4 f = *(const float4*)(src + (size_t)r * DHEAD + c);
    tile[r][c] = f.x; tile[r][c + 1] = f.y; tile[r][c + 2] = f.z; tile[r][c + 3] = f.w;
  }
  __syncthreads();
  unsigned short* dst = stT + (size_t)h * 16384 + (size_t)e0 * DHEAD + d0;
#pragma unroll
  for (int p = 0; p < 2; p++) {
    int idx = tid + p * 256;
    int er = idx >> 3, doff = (idx & 7) * 8;
    bf16x8 o;
#pragma unroll
    for (int j = 0; j < 8; j++) o[j] = (short)f2bf(tile[doff + j][er]);
    *(bf16x8*)(dst + (size_t)er * DHEAD + doff) = o;
  }
}

// ---------------- retention v8: split-j x2, private buffers, no atomics -----
// R7 lesson: split-j works but zero+gn+atomic overhead ate the gain. v8:
// 2 chunks, each writes its own R32 slab with plain stores (partials are
// disjoint); gn sums the two slabs. Blocks with no work write zeros.
// Inner loop identical to v6 (clean vmem window, counted vmcnt, raw barriers).
__global__ __launch_bounds__(256) void retention_split(const unsigned short* __restrict__ qb,
                                                       const unsigned short* __restrict__ kb,
                                                       const unsigned short* __restrict__ vT,
                                                       const unsigned short* __restrict__ stT,
                                                       const float* __restrict__ A,
                                                       float* __restrict__ R32) {
  __shared__ __align__(16) unsigned short ks[2][64 * 128];
  __shared__ __align__(16) unsigned short vs[2][128 * 64];
  __shared__ __align__(16) unsigned short Ss[64 * 72];
  int h = blockIdx.x;
  int i0 = blockIdx.y * 64;
  int jc = blockIdx.z;
  int jlo = jc * 1024;
  int jhi = min(i0, jlo + 960);         // last j-tile start in this chunk
  int tid = threadIdx.x;
  int wave = tid >> 6, lane = tid & 63, quad = lane >> 4, m16 = lane & 15;
  const float* Ah = A + (size_t)h * SQLEN;
  float c = Ah[i0];
  int rq = wave * 16 + m16;
  float* Rc = R32 + (size_t)jc * 4194304;   // private slab per chunk

  // wave-parallel scan for first non-skipped j-tile (prefix is monotone)
  bool skipl = false;
  if (lane < 32) {
    int j0l = lane * 64;
    if (j0l <= i0) skipl = (c - Ah[j0l + 63] < -87.f);
  }
  unsigned long long smask = __ballot(skipl);
  int j_start = 64 * (int)__builtin_ctzll(~smask);
  int j_begin = max(j_start, jlo);
  bool work = (jlo <= i0) && (j_begin <= jhi);   // uniform
  bool crossw = (jc == 0) && (c > -87.f);        // uniform

  floatx4 acc[8];
#pragma unroll
  for (int et = 0; et < 8; et++) acc[et] = (floatx4){0.f, 0.f, 0.f, 0.f};

  if (work || crossw) {
    const unsigned short* qh = qb + ((size_t)h * SQLEN + i0 + rq) * DHEAD;
    bf16x8 qf[4];
#pragma unroll
    for (int dc = 0; dc < 4; dc++)
      qf[dc] = *(const bf16x8*)(qh + dc * 32 + quad * 8);
    float ei = __expf(Ah[i0 + rq] - c);

    const unsigned short* khb = kb + (size_t)h * SQLEN * DHEAD;
    const unsigned short* vhb = vT + (size_t)h * (DHEAD * SQLEN);

#define STAGE_KV(b_, j0_) do { \
    const unsigned short* kh_ = khb + (size_t)(j0_) * DHEAD; \
    const unsigned short* vh_ = vhb + (j0_); \
    _Pragma("unroll") for (int p = 0; p < 4; p++) { \
      int cch = tid + p * 256; \
      int r_ = cch >> 4, kp_ = (cch & 15) ^ (r_ & 7); \
      GLD(kh_ + (size_t)r_ * DHEAD + kp_ * 8, &ks[b_][0] + cch * 8); \
      int e_ = cch >> 3, tp_ = (cch & 7) ^ (e_ & 7); \
      GLD(vh_ + (size_t)e_ * SQLEN + tp_ * 8, &vs[b_][0] + cch * 8); \
    } \
  } while (0)

    if (work) STAGE_KV(0, j_begin);     // latency hides under cross term

    if (crossw) {
      const unsigned short* sp = stT + (size_t)h * 16384;
      float ecr[4];
#pragma unroll
      for (int r = 0; r < 4; r++) ecr[r] = __expf(Ah[i0 + wave * 16 + quad * 4 + r]);
#pragma unroll
      for (int et = 0; et < 8; et++) {
#pragma unroll
        for (int dc = 0; dc < 4; dc++) {
          bf16x8 sf = *(const bf16x8*)(sp + (et * 16 + m16) * DHEAD + dc * 32 + quad * 8);
          acc[et] = __builtin_amdgcn_mfma_f32_16x16x32_bf16(qf[dc], sf, acc[et], 0, 0, 0);
        }
#pragma unroll
        for (int r = 0; r < 4; r++) acc[et][r] *= ecr[r];
      }
    }

    if (work) {
      int cur = 0;
      for (int j0 = j_begin; j0 <= jhi; j0 += 64) {
        int nxt = j0 + 64;
        // decay source issued BEFORE the staging GLDs (v6 lesson): the loop's
        // vmem window after this point is exactly the 8 GLDs.
        float av = Ah[j0 + lane];
        __builtin_amdgcn_sched_barrier(0);
        if (nxt <= jhi) {
          STAGE_KV(cur ^ 1, nxt);
          asm volatile("s_waitcnt vmcnt(8) lgkmcnt(0)" ::: "memory");
        } else {
          asm volatile("s_waitcnt vmcnt(0) lgkmcnt(0)" ::: "memory");
        }
        __builtin_amdgcn_sched_barrier(0);
        asm volatile("s_barrier" ::: "memory");  // cur landed globally

        float dj = __expf(c - av);

        bool diag = (j0 == i0);
        const unsigned short* ksc = &ks[cur][0];
        const unsigned short* vsc = &vs[cur][0];
#pragma unroll
        for (int jt = 0; jt < 4; jt++) {
          floatx4 s = (floatx4){0.f, 0.f, 0.f, 0.f};
#pragma unroll
          for (int dc = 0; dc < 4; dc++) {
            int rk = jt * 16 + m16;
            bf16x8 kf = *(const bf16x8*)(ksc + rk * 128 + (((dc * 4 + quad) ^ (rk & 7)) * 8));
            s = __builtin_amdgcn_mfma_f32_16x16x32_bf16(kf, qf[dc], s, 0, 0, 0);
          }
          int jb = jt * 16 + quad * 4;
          float d0 = __shfl(dj, jb + 0);
          float d1 = __shfl(dj, jb + 1);
          float d2 = __shfl(dj, jb + 2);
          float d3 = __shfl(dj, jb + 3);
          ushort4 pk;
          pk.x = f2bf((diag && (jb + 0 > rq)) ? 0.f : s[0] * ei * d0);
          pk.y = f2bf((diag && (jb + 1 > rq)) ? 0.f : s[1] * ei * d1);
          pk.z = f2bf((diag && (jb + 2 > rq)) ? 0.f : s[2] * ei * d2);
          pk.w = f2bf((diag && (jb + 3 > rq)) ? 0.f : s[3] * ei * d3);
          *(ushort4*)(Ss + rq * 72 + jb) = pk;
        }

        bf16x8 sfr[2];
#pragma unroll
        for (int kc = 0; kc < 2; kc++)
          sfr[kc] = *(const bf16x8*)(Ss + rq * 72 + kc * 32 + quad * 8);
#pragma unroll
        for (int et = 0; et < 8; et++) {
#pragma unroll
          for (int kc = 0; kc < 2; kc++) {
            int e = et * 16 + m16;
            bf16x8 vf = *(const bf16x8*)(vsc + e * 64 + (((kc * 4 + quad) ^ (e & 7)) * 8));
            acc[et] = __builtin_amdgcn_mfma_f32_16x16x32_bf16(sfr[kc], vf, acc[et], 0, 0, 0);
          }
        }
        asm volatile("s_barrier" ::: "memory");
        cur ^= 1;
      }
    }
#undef STAGE_KV
  }

  // plain stores into this chunk's private slab (zeros if no work)
#pragma unroll
  for (int r = 0; r < 4; r++) {
    int row = i0 + wave * 16 + quad * 4 + r;
    size_t o = (size_t)row * DMODEL + h * DHEAD;
#pragma unroll
    for (int et = 0; et < 8; et++)
      Rc[o + et * 16 + m16] = acc[et][r];
  }
}

// ------ group norm over R32[0]+R32[1] -> rn fp32 + rnb bf16 -----------------
__global__ __launch_bounds__(256) void gn_kernel(const float* __restrict__ R32,
                                                 const float* __restrict__ gn_w,
                                                 const float* __restrict__ gn_b,
                                                 float* __restrict__ rn,
                                                 unsigned short* __restrict__ rnb) {
  int row = blockIdx.x;
  int tid = threadIdx.x;
  size_t base = (size_t)row * DMODEL + tid * 8;
  float4 a0 = *(const float4*)(R32 + base);
  float4 b0 = *(const float4*)(R32 + base + 4);
  float4 a1 = *(const float4*)(R32 + 4194304 + base);
  float4 b1 = *(const float4*)(R32 + 4194304 + base + 4);
  float v[8] = {a0.x + a1.x, a0.y + a1.y, a0.z + a1.z, a0.w + a1.w,
                b0.x + b1.x, b0.y + b1.y, b0.z + b1.z, b0.w + b1.w};
  float s = 0.f, ss = 0.f;
#pragma unroll
  for (int k = 0; k < 8; k++) { s += v[k]; ss += v[k] * v[k]; }
  // reduce across the 16 threads of this head (tid bits 0-3, same wave)
#pragma unroll
  for (int off = 8; off > 0; off >>= 1) {
    s += __shfl_xor(s, off);
    ss += __shfl_xor(ss, off);
  }
  float mu = s * (1.f / 128.f);
  float var = ss * (1.f / 128.f) - mu * mu;
  float inv = rsqrtf(var + 1e-5f);
  int col0 = tid * 8;
  const float* wp = gn_w + col0;
  const float* bp = gn_b + col0;
  float o[8];
  ushort4 ob[2];
#pragma unroll
  for (int k = 0; k < 8; k++) {
    o[k] = (v[k] - mu) * inv * wp[k] + bp[k];
    ((unsigned short*)ob)[k] = f2bf(o[k]);
  }
  float* rp = rn + (size_t)row * DMODEL + col0;
  *(float4*)rp = (float4){o[0], o[1], o[2], o[3]};
  *(float4*)(rp + 4) = (float4){o[4], o[5], o[6], o[7]};
  *(ushort4*)(rnb + (size_t)row * DMODEL + col0) = ob[0];
  *(ushort4*)(rnb + (size_t)row * DMODEL + col0 + 4) = ob[1];
}

// -------- new_state GEMM: P[h,chunk] = kT_s[:,krange] @ vT[:,krange]^T ------
__global__ __launch_bounds__(256) void state_gemm(const unsigned short* __restrict__ kT,
                                                  const unsigned short* __restrict__ vT,
                                                  float* __restrict__ P) {
  __shared__ __align__(16) unsigned short As[128 * 32];
  __shared__ __align__(16) unsigned short Bs[128 * 32];
  int chunk = blockIdx.x, h = blockIdx.y;
  int tid = threadIdx.x;
  int wave = tid >> 6, lane = tid & 63;
  int wm = wave >> 1, wn = wave & 1;
  int quad = lane >> 4, m16 = lane & 15;
  const unsigned short* Ab = kT + (size_t)h * (DHEAD * SQLEN);
  const unsigned short* Bb = vT + (size_t)h * (DHEAD * SQLEN);

  floatx4 acc[4][4];
#pragma unroll
  for (int i = 0; i < 4; i++)
#pragma unroll
    for (int j = 0; j < 4; j++) acc[i][j] = (floatx4){0.f, 0.f, 0.f, 0.f};

  int c0 = tid, c1 = tid + 256;
  int r0c = c0 >> 2, q0c = (c0 & 3) * 8;
  int r1c = c1 >> 2, q1c = (c1 & 3) * 8;

  for (int k0 = chunk * 256; k0 < chunk * 256 + 256; k0 += 32) {
    __builtin_amdgcn_global_load_lds(
        (const __attribute__((address_space(1))) unsigned int*)(Ab + (size_t)r0c * SQLEN + k0 + q0c),
        (__attribute__((address_space(3))) unsigned int*)(As + c0 * 8), 16, 0, 0);
    __builtin_amdgcn_global_load_lds(
        (const __attribute__((address_space(1))) unsigned int*)(Ab + (size_t)r1c * SQLEN + k0 + q1c),
        (__attribute__((address_space(3))) unsigned int*)(As + c1 * 8), 16, 0, 0);
    __builtin_amdgcn_global_load_lds(
        (const __attribute__((address_space(1))) unsigned int*)(Bb + (size_t)r0c * SQLEN + k0 + q0c),
        (__attribute__((address_space(3))) unsigned int*)(Bs + c0 * 8), 16, 0, 0);
    __builtin_amdgcn_global_load_lds(
        (const __attribute__((address_space(1))) unsigned int*)(Bb + (size_t)r1c * SQLEN + k0 + q1c),
        (__attribute__((address_space(3))) unsigned int*)(Bs + c1 * 8), 16, 0, 0);
    __syncthreads();

    bf16x8 af[4], bfr[4];
#pragma unroll
    for (int i = 0; i < 4; i++)
      af[i] = *(const bf16x8*)(As + (wm * 64 + i * 16 + m16) * 32 + quad * 8);
#pragma unroll
    for (int j = 0; j < 4; j++)
      bfr[j] = *(const bf16x8*)(Bs + (wn * 64 + j * 16 + m16) * 32 + quad * 8);
#pragma unroll
    for (int i = 0; i < 4; i++)
#pragma unroll
      for (int j = 0; j < 4; j++)
        acc[i][j] = __builtin_amdgcn_mfma_f32_16x16x32_bf16(af[i], bfr[j], acc[i][j], 0, 0, 0);
    __syncthreads();
  }

  float* Pp = P + (size_t)(h * 8 + chunk) * 16384;
#pragma unroll
  for (int i = 0; i < 4; i++)
#pragma unroll
    for (int j = 0; j < 4; j++) {
      int rr = wm * 64 + i * 16 + quad * 4;
      int cc = wn * 64 + j * 16 + m16;
#pragma unroll
      for (int r = 0; r < 4; r++)
        Pp[(size_t)(rr + r) * DHEAD + cc] = acc[i][j][r];
    }
}

__global__ __launch_bounds__(256) void state_combine(const float* __restrict__ P,
                                                     const float* __restrict__ state,
                                                     const float* __restrict__ A,
                                                     float* __restrict__ out_state) {
  int idx = blockIdx.x * 256 + threadIdx.x;
  int h = idx >> 14;
  int de = idx & 16383;
  float B = A[(size_t)h * SQLEN + SQLEN - 1];
  float s = __expf(B) * state[idx];
#pragma unroll
  for (int c = 0; c < 8; c++) s += P[(size_t)(h * 8 + c) * 16384 + de];
  out_state[idx] = s;
}

extern "C" void kernel_launch(void* const* d_in, const int* in_sizes, int n_in,
                              void* d_out, int out_size, void* d_ws, size_t ws_size,
                              hipStream_t stream) {
  const float* x = (const float*)d_in[0];
  const float* state = (const float*)d_in[1];
  const float* W_qkv = (const float*)d_in[2];
  const float* W_alpha = (const float*)d_in[3];
  const float* b_alpha = (const float*)d_in[4];
  const float* alpha_base = (const float*)d_in[5];
  const float* gn_w = (const float*)d_in[6];
  const float* gn_b = (const float*)d_in[7];
  const float* W_out = (const float*)d_in[8];
  const float* W_gate = (const float*)d_in[9];
  const int* offset = (const int*)d_in[10];

  float* ws = (float*)d_ws;
  float* qkv = ws;                      // [0,12582912) alive gemm -> xpos
  float* P   = ws;                      // [0,2097152) after retention (qkv dead)
  float* R32 = ws + 4194304;            // 2 slabs: [4194304,12582912) after xpos
  float* rn  = ws + 29360128;
  float* araw = ws + 33554432;
  float* Acum = ws + 33587200;

  unsigned short* xb    = (unsigned short*)(ws + 12582912);
  unsigned short* Wqkvb = (unsigned short*)(ws + 16777216);
  unsigned short* qb    = (unsigned short*)(ws + 12582912);
  unsigned short* kb    = (unsigned short*)(ws + 14680064);
  unsigned short* vb    = (unsigned short*)(ws + 16777216);
  unsigned short* kT_s  = (unsigned short*)(ws + 18874368);
  unsigned short* vT_b  = (unsigned short*)(ws + 20971520);
  unsigned short* stT_b = (unsigned short*)(ws + 23068672);
  unsigned short* rnb   = (unsigned short*)(ws + 25165824);
  unsigned short* Wgateb = (unsigned short*)(ws + 14680064);
  unsigned short* Woutb  = (unsigned short*)(ws + 16777216);
  unsigned short* Hb     = (unsigned short*)(ws + 18874368);

  float* out = (float*)d_out;
  float* out_state = out + 4194304;

  dim3 blk(256);
  f2b2_kernel<<<dim3(16384), blk, 0, stream>>>((const float4*)x, (ushort4*)xb,
                                               (const float4*)W_qkv, (ushort4*)Wqkvb, 4096);
  gemm256_nt<<<dim3(24, 8), dim3(512), 0, stream>>>(xb, Wqkvb, qkv, 2048, 6144, 2048);

  alpha_kernel<<<dim3(512), blk, 0, stream>>>(x, W_alpha, b_alpha, alpha_base, araw);
  cumsum_kernel<<<dim3(16), blk, 0, stream>>>(araw, Acum);
  xpos_kernel<<<dim3(8192), blk, 0, stream>>>(qkv, araw, offset, qb, kb, vb);
  transpose_kv_kernel<<<dim3(32, 2, 32), blk, 0, stream>>>(kb, vb, Acum, kT_s, vT_b);
  transpose_state_kernel<<<dim3(2, 2, 16), blk, 0, stream>>>(state, stT_b);

  retention_split<<<dim3(16, 32, 2), blk, 0, stream>>>(qb, kb, vT_b, stT_b, Acum, R32);
  gn_kernel<<<dim3(2048), blk, 0, stream>>>(R32, gn_w, gn_b, rn, rnb);

  state_gemm<<<dim3(8, 16), blk, 0, stream>>>(kT_s, vT_b, P);
  state_combine<<<dim3(1024), blk, 0, stream>>>(P, state, Acum, out_state);

  f2b2_kernel<<<dim3(8192), blk, 0, stream>>>((const float4*)W_gate, (ushort4*)Wgateb,
                                              (const float4*)W_out, (ushort4*)Woutb, 4096);
  gemm_swish_nt<<<dim3(16, 16), blk, 0, stream>>>(rnb, Wgateb, rn, Hb, 2048, 2048, 2048);
  gemm_bf16_nt<<<dim3(16, 16), blk, 0, stream>>>(Hb, Woutb, out, 2048, 2048, 2048);
}

// Round 10
// 397.644 us; speedup vs baseline: 1.0811x; 1.0648x over previous
//
#include <hip/hip_runtime.h>
#include <cstddef>

#define SQLEN 2048
#define DMODEL 2048
#define NHEADS 16
#define DHEAD 128

typedef __attribute__((ext_vector_type(8))) short bf16x8;
typedef __attribute__((ext_vector_type(4))) float floatx4;

__device__ __forceinline__ unsigned short f2bf(float f) {
  union { float f; unsigned u; } c; c.f = f;
  unsigned u = c.u;
  unsigned r = u + 0x7fffu + ((u >> 16) & 1u);
  return (unsigned short)(r >> 16);
}
__device__ __forceinline__ float bf2f(unsigned short s) {
  union { unsigned u; float f; } c; c.u = ((unsigned)s) << 16;
  return c.f;
}

// ---------------- fp32 -> bf16 convert (vectorized) -------------------------
__global__ __launch_bounds__(256) void f2b_kernel(const float4* __restrict__ in,
                                                  ushort4* __restrict__ out) {
  int i = blockIdx.x * 256 + threadIdx.x;
  float4 v = in[i];
  ushort4 o;
  o.x = f2bf(v.x); o.y = f2bf(v.y); o.z = f2bf(v.z); o.w = f2bf(v.w);
  out[i] = o;
}

// two-array variant (two tensors in one launch)
__global__ __launch_bounds__(256) void f2b2_kernel(const float4* __restrict__ in0,
                                                   ushort4* __restrict__ out0,
                                                   const float4* __restrict__ in1,
                                                   ushort4* __restrict__ out1,
                                                   int half_blocks) {
  int b = blockIdx.x;
  const float4* in = (b < half_blocks) ? in0 : in1;
  ushort4* out = (b < half_blocks) ? out0 : out1;
  int i = (b < half_blocks ? b : b - half_blocks) * 256 + threadIdx.x;
  float4 v = in[i];
  ushort4 o;
  o.x = f2bf(v.x); o.y = f2bf(v.y); o.z = f2bf(v.z); o.w = f2bf(v.w);
  out[i] = o;
}

// =================== 256x256 8-phase bf16 GEMM (C = A @ B^T) ================
#define GLD(srcp, dstp) __builtin_amdgcn_global_load_lds( \
    (const __attribute__((address_space(1))) unsigned int*)(srcp), \
    (__attribute__((address_space(3))) unsigned int*)(dstp), 16, 0, 0)

__global__ __launch_bounds__(512, 2) void gemm256_nt(const unsigned short* __restrict__ A,
                                                     const unsigned short* __restrict__ B,
                                                     float* __restrict__ C,
                                                     int M, int N, int K) {
  __shared__ __align__(16) unsigned short lds[65536];  // 128 KiB
  int tid = threadIdx.x;
  int wave = tid >> 6, lane = tid & 63;
  int wm = wave >> 2, wn = wave & 3;            // 2 x 4 wave grid
  int quad = lane >> 4, m16 = lane & 15;
  int sw = m16 & 7;

  int nTN = gridDim.x;
  int lin = blockIdx.y * nTN + blockIdx.x;
  int nwg = gridDim.x * gridDim.y;
  int swzb = (nwg & 7) == 0 ? ((lin & 7) * (nwg >> 3) + (lin >> 3)) : lin;
  int row0 = (swzb / nTN) * 256, col0 = (swzb % nTN) * 256;

  const int nkt = K >> 6;    // K-tiles of 64
  const int nit = K >> 7;    // loop iters (2 tiles each)

  int srow = tid >> 3;
  int scol8 = (((tid & 7) ^ ((tid >> 3) & 7)) * 8);  // pre-swizzled global col

  bf16x8 a0[2][4], a1[2][4], bb[2][2];
  floatx4 acc[2][2][4][2];
#pragma unroll
  for (int a = 0; a < 2; a++)
#pragma unroll
    for (int b = 0; b < 2; b++)
#pragma unroll
      for (int c = 0; c < 4; c++)
#pragma unroll
        for (int d = 0; d < 2; d++) acc[a][b][c][d] = (floatx4){0.f, 0.f, 0.f, 0.f};

#define STAGE(t_, ab_, h_) do { \
    int t2_ = (t_); if (t2_ >= nkt) t2_ -= nkt; \
    const unsigned short* gp_ = (ab_) ? B : A; \
    int rb_ = ((ab_) ? col0 : row0) + (h_) * 128 + srow; \
    int kk_ = t2_ * 64 + scol8; \
    unsigned bs_ = ((unsigned)((t_) & 1)) * 32768u + (ab_) * 16384u + (h_) * 8192u; \
    GLD(gp_ + (size_t)rb_ * K + kk_, lds + bs_ + tid * 8); \
    GLD(gp_ + (size_t)(rb_ + 64) * K + kk_, lds + bs_ + 4096 + tid * 8); \
  } while (0)

#define VMW asm volatile("s_waitcnt vmcnt(4)" ::: "memory");

#define RDA(dst_, BUF_, MH_) do { \
    const unsigned short* Ab_ = lds + (BUF_) * 32768 + (MH_) * 8192; \
    _Pragma("unroll") for (int ks = 0; ks < 2; ks++) \
      _Pragma("unroll") for (int fi = 0; fi < 4; fi++) \
        dst_[ks][fi] = *(const bf16x8*)(Ab_ + (wm * 64 + fi * 16 + m16) * 64 + (((ks * 4 + quad) ^ sw) * 8)); \
  } while (0)

#define RDB(BUF_, NH_) do { \
    const unsigned short* Bb_ = lds + (BUF_) * 32768 + 16384 + (NH_) * 8192; \
    _Pragma("unroll") for (int ks = 0; ks < 2; ks++) \
      _Pragma("unroll") for (int gj = 0; gj < 2; gj++) \
        bb[ks][gj] = *(const bf16x8*)(Bb_ + (wn * 32 + gj * 16 + m16) * 64 + (((ks * 4 + quad) ^ sw) * 8)); \
  } while (0)

#define MM(A_, MH_, NH_) \
    _Pragma("unroll") for (int ks = 0; ks < 2; ks++) \
      _Pragma("unroll") for (int fi = 0; fi < 4; fi++) \
        _Pragma("unroll") for (int gj = 0; gj < 2; gj++) \
          acc[MH_][NH_][fi][gj] = __builtin_amdgcn_mfma_f32_16x16x32_bf16( \
              A_[ks][fi], bb[ks][gj], acc[MH_][NH_][fi][gj], 0, 0, 0);

#define PH(RD_, STG_, W_, MM_) do { \
    RD_; \
    STG_; \
    W_ \
    __builtin_amdgcn_s_barrier(); \
    asm volatile("s_waitcnt lgkmcnt(0)" ::: "memory"); \
    __builtin_amdgcn_sched_barrier(0); \
    __builtin_amdgcn_s_setprio(1); \
    MM_ \
    __builtin_amdgcn_s_setprio(0); \
    __builtin_amdgcn_sched_barrier(0); \
    __builtin_amdgcn_s_barrier(); \
  } while (0)

  STAGE(0, 1, 0);
  STAGE(0, 0, 0);
  STAGE(0, 0, 1);
  STAGE(0, 1, 1);
  STAGE(1, 1, 0);
  STAGE(1, 0, 0);
  asm volatile("s_waitcnt vmcnt(4)" ::: "memory");
  __builtin_amdgcn_s_barrier();

  for (int it = 0; it < nit; ++it) {
    int T = it * 2;
    PH(RDA(a0, 0, 0); RDB(0, 0), STAGE(T + 1, 0, 1), , MM(a0, 0, 0));
    PH(RDA(a1, 0, 1),            STAGE(T + 1, 1, 1), , MM(a1, 1, 0));
    PH(RDB(0, 1),                STAGE(T + 2, 1, 0), , MM(a0, 0, 1));
    PH(,                         STAGE(T + 2, 0, 0), VMW, MM(a1, 1, 1));
    PH(RDA(a0, 1, 0); RDB(1, 0), STAGE(T + 2, 0, 1), , MM(a0, 0, 0));
    PH(RDA(a1, 1, 1),            STAGE(T + 2, 1, 1), , MM(a1, 1, 0));
    PH(RDB(1, 1),                STAGE(T + 3, 1, 0), , MM(a0, 0, 1));
    PH(,                         STAGE(T + 3, 0, 0), VMW, MM(a1, 1, 1));
  }

#pragma unroll
  for (int mh = 0; mh < 2; mh++)
#pragma unroll
    for (int nh = 0; nh < 2; nh++)
#pragma unroll
      for (int fi = 0; fi < 4; fi++)
#pragma unroll
        for (int gj = 0; gj < 2; gj++) {
          int rr = row0 + mh * 128 + wm * 64 + fi * 16 + quad * 4;
          int cc = col0 + nh * 128 + wn * 32 + gj * 16 + m16;
#pragma unroll
          for (int r = 0; r < 4; r++)
            C[(size_t)(rr + r) * N + cc] = acc[mh][nh][fi][gj][r];
        }
#undef PH
#undef MM
#undef RDB
#undef RDA
#undef VMW
#undef STAGE
}

// ============ tail GEMM: 128x64 tile, dbuf K-loop, counted vmcnt ============
// C[M,N] = A[M,K] @ B[N,K]^T. 256 thr / 4 waves (2M x 2N), wave tile 64x32.
// BK=32 double-buffered (24 KB LDS). grid (N/64, M/128) = 512 blocks = 2/CU.
// v6 pattern: stage next tile, s_waitcnt vmcnt(3) (3 just-issued in flight),
// raw s_barrier -- no drain. Slot swizzle ^(row&3), pre-swizzled source.
// EPI: 0 = fp32 C store; 1 = swish(g)*rn -> bf16 Hb.
template <int EPI>
__device__ __forceinline__ void gemm_tail_body(const unsigned short* __restrict__ A,
                                               const unsigned short* __restrict__ B,
                                               const float* __restrict__ rn,
                                               float* __restrict__ C,
                                               unsigned short* __restrict__ Hb,
                                               int M, int N, int K) {
  __shared__ __align__(16) unsigned short As[2][128 * 32];
  __shared__ __align__(16) unsigned short Bs[2][64 * 32];
  int tid = threadIdx.x;
  int wave = tid >> 6, lane = tid & 63;
  int wm = wave >> 1, wn = wave & 1;
  int quad = lane >> 4, m16 = lane & 15;
  int row0 = blockIdx.y * 128, col0 = blockIdx.x * 64;
  int sw3 = m16 & 3;

  floatx4 acc[4][2];
#pragma unroll
  for (int i = 0; i < 4; i++)
#pragma unroll
    for (int j = 0; j < 2; j++) acc[i][j] = (floatx4){0.f, 0.f, 0.f, 0.f};

  // staging geometry: A chunks c=tid, tid+256 (r=c>>2, slot=c&3); B chunk c=tid<256
  int rA0 = tid >> 2, sA0 = tid & 3;
  int rA1 = (tid + 256) >> 2, sA1 = tid & 3;  // (tid+256)&3 == tid&3
  const size_t sK = (size_t)K;

#define TSTAGE(b_, kt_) do { \
    int k0_ = (kt_) * 32; \
    GLD(A + (size_t)(row0 + rA0) * sK + k0_ + ((sA0 ^ (rA0 & 3)) * 8), &As[b_][0] + tid * 8); \
    GLD(A + (size_t)(row0 + rA1) * sK + k0_ + ((sA1 ^ (rA1 & 3)) * 8), &As[b_][0] + (tid + 256) * 8); \
    GLD(B + (size_t)(col0 + rA0) * sK + k0_ + ((sA0 ^ (rA0 & 3)) * 8), &Bs[b_][0] + tid * 8); \
  } while (0)

  const int nkt = K >> 5;
  TSTAGE(0, 0);
  int cur = 0;
  for (int kt = 0; kt < nkt; ++kt) {
    if (kt < nkt - 1) {
      TSTAGE(cur ^ 1, kt + 1);
      asm volatile("s_waitcnt vmcnt(3)" ::: "memory");  // cur's 3 landed (own wave)
    } else {
      asm volatile("s_waitcnt vmcnt(0)" ::: "memory");
    }
    __builtin_amdgcn_sched_barrier(0);
    asm volatile("s_barrier" ::: "memory");  // cur landed globally

    bf16x8 af[4], bf[2];
#pragma unroll
    for (int fi = 0; fi < 4; fi++)
      af[fi] = *(const bf16x8*)(&As[cur][0] + (wm * 64 + fi * 16 + m16) * 32 + ((quad ^ sw3) * 8));
#pragma unroll
    for (int gj = 0; gj < 2; gj++)
      bf[gj] = *(const bf16x8*)(&Bs[cur][0] + (wn * 32 + gj * 16 + m16) * 32 + ((quad ^ sw3) * 8));
#pragma unroll
    for (int fi = 0; fi < 4; fi++)
#pragma unroll
      for (int gj = 0; gj < 2; gj++)
        acc[fi][gj] = __builtin_amdgcn_mfma_f32_16x16x32_bf16(af[fi], bf[gj], acc[fi][gj], 0, 0, 0);

    // reads of buf[cur] consumed (compiler lgkmcnt before MFMA); barrier
    // orders buffer reuse by next iteration's staging
    asm volatile("s_barrier" ::: "memory");
    cur ^= 1;
  }
#undef TSTAGE

#pragma unroll
  for (int fi = 0; fi < 4; fi++)
#pragma unroll
    for (int gj = 0; gj < 2; gj++) {
      int rr = row0 + wm * 64 + fi * 16 + quad * 4;
      int cc = col0 + wn * 32 + gj * 16 + m16;
#pragma unroll
      for (int r = 0; r < 4; r++) {
        if (EPI == 0) {
          C[(size_t)(rr + r) * N + cc] = acc[fi][gj][r];
        } else {
          float g = acc[fi][gj][r];
          float rv = rn[(size_t)(rr + r) * N + cc];
          float hh = g / (1.f + __expf(-g)) * rv;
          Hb[(size_t)(rr + r) * N + cc] = f2bf(hh);
        }
      }
    }
}

__global__ __launch_bounds__(256) void gemm_tail_out(const unsigned short* __restrict__ A,
                                                     const unsigned short* __restrict__ B,
                                                     float* __restrict__ C,
                                                     int M, int N, int K) {
  gemm_tail_body<0>(A, B, nullptr, C, nullptr, M, N, K);
}

__global__ __launch_bounds__(256) void gemm_tail_swish(const unsigned short* __restrict__ A,
                                                       const unsigned short* __restrict__ B,
                                                       const float* __restrict__ rn,
                                                       unsigned short* __restrict__ Hb,
                                                       int M, int N, int K) {
  gemm_tail_body<1>(A, B, rn, nullptr, Hb, M, N, K);
}

// ---------------- alpha: block = 4 t-rows staged in LDS, loop 16 heads ------
__global__ __launch_bounds__(256) void alpha_kernel(const float* __restrict__ x,
                                                    const float* __restrict__ W_alpha,
                                                    const float* __restrict__ b_alpha,
                                                    const float* __restrict__ alpha_base,
                                                    float* __restrict__ a_raw) {
  __shared__ float xs[4][2048];
  int tid = threadIdx.x;
  int t0 = blockIdx.x * 4;
#pragma unroll
  for (int p = 0; p < 8; p++) {
    int idx = tid + p * 256;
    int row = idx >> 9, c4 = idx & 511;
    *(float4*)&xs[row][c4 * 4] = *(const float4*)(x + (size_t)(t0 + row) * DMODEL + c4 * 4);
  }
  __syncthreads();
  int w = tid >> 6, lane = tid & 63;
  int t = t0 + w;
#pragma unroll
  for (int h = 0; h < NHEADS; h++) {
    const float4* wr = (const float4*)(W_alpha + (size_t)h * DMODEL);
    float s = 0.f;
#pragma unroll
    for (int i = lane; i < 512; i += 64) {
      float4 a = *(const float4*)&xs[w][i * 4];
      float4 b = wr[i];
      s += a.x * b.x + a.y * b.y + a.z * b.z + a.w * b.w;
    }
#pragma unroll
    for (int off = 32; off > 0; off >>= 1) s += __shfl_down(s, off);
    if (lane == 0) {
      float sig = 1.f / (1.f + __expf(-(s + b_alpha[h])));
      a_raw[(size_t)h * SQLEN + t] = alpha_base[h] * 8.f * sig;
    }
  }
}

// ---------------- cumsum ----------------------------------------------------
__global__ __launch_bounds__(256) void cumsum_kernel(const float* __restrict__ a_raw,
                                                     float* __restrict__ A) {
  int h = blockIdx.x;
  __shared__ float part[256];
  int tid = threadIdx.x;
  float v[8];
  float s = 0.f;
#pragma unroll
  for (int i = 0; i < 8; i++) {
    v[i] = a_raw[(size_t)h * SQLEN + tid * 8 + i];
    s += v[i];
  }
  part[tid] = s;
  __syncthreads();
  for (int off = 1; off < 256; off <<= 1) {
    float tmp = (tid >= off) ? part[tid - off] : 0.f;
    __syncthreads();
    part[tid] += tmp;
    __syncthreads();
  }
  float run = (tid > 0) ? part[tid - 1] : 0.f;
#pragma unroll
  for (int i = 0; i < 8; i++) {
    run += v[i];
    A[(size_t)h * SQLEN + tid * 8 + i] = run;
  }
}

// ---------------- xPos: emit q,k,v directly as bf16 [h][t][d] ---------------
__global__ __launch_bounds__(256) void xpos_kernel(const float* __restrict__ qkv,
                                                   const float* __restrict__ a_raw,
                                                   const int* __restrict__ offset_p,
                                                   unsigned short* __restrict__ qb,
                                                   unsigned short* __restrict__ kb,
                                                   unsigned short* __restrict__ vb) {
  int idx = blockIdx.x * 256 + threadIdx.x;
  int j = idx & 63;
  int t = (idx >> 6) & 2047;
  int h = idx >> 17;
  float pos = (float)(t + offset_p[0]);
  float freq = exp2f(-(float)j * (13.287712379549449f / 64.f));
  float ang = pos * freq;
  float sn = __sinf(ang), cs = __cosf(ang);
  float zeta = (2.f * (float)j + 51.2f) / 179.2f;
  float lzp = __log2f(zeta) * pos * (1.f / 512.f);
  float sc = exp2f(lzp);
  float sci = exp2f(-lzp);
  const float* row = qkv + (size_t)t * (3 * DMODEL);
  int base = h * DHEAD + j;
  float q1 = row[base], q2 = row[base + 64];
  float k1 = row[DMODEL + base], k2 = row[DMODEL + base + 64];
  float v1 = row[2 * DMODEL + base], v2 = row[2 * DMODEL + base + 64];
  size_t o = ((size_t)h * SQLEN + t) * DHEAD + j;
  qb[o] = f2bf((q1 * cs - q2 * sn) * sc);
  qb[o + 64] = f2bf((q2 * cs + q1 * sn) * sc);
  float km = (1.f - __expf(a_raw[(size_t)h * SQLEN + t])) * sci;
  kb[o] = f2bf((k1 * cs - k2 * sn) * km);
  kb[o + 64] = f2bf((k2 * cs + k1 * sn) * km);
  vb[o] = f2bf(v1);
  vb[o + 64] = f2bf(v2);
}

// ------- transpose kb/vb [h][t][d] -> [h][d][t]; k gets exp(B-A[t]) scale ---
__global__ __launch_bounds__(256) void transpose_kv_kernel(const unsigned short* __restrict__ kb,
                                                           const unsigned short* __restrict__ vb,
                                                           const float* __restrict__ A,
                                                           unsigned short* __restrict__ kT,
                                                           unsigned short* __restrict__ vT) {
  __shared__ __align__(16) unsigned short tile[64][72];
  int h = blockIdx.z >> 1, sel = blockIdx.z & 1;
  int t0 = blockIdx.x * 64, d0 = blockIdx.y * 64;
  int tid = threadIdx.x;
  const unsigned short* src = (sel ? vb : kb) + ((size_t)h * SQLEN + t0) * DHEAD + d0;
  unsigned short* dst = (sel ? vT : kT) + (size_t)h * (DHEAD * SQLEN) + (size_t)d0 * SQLEN + t0;
  float B = A[(size_t)h * SQLEN + SQLEN - 1];
#pragma unroll
  for (int p = 0; p < 2; p++) {
    int c = tid + p * 256;
    int r = c >> 3, off = (c & 7) * 8;
    bf16x8 in = *(const bf16x8*)(src + (size_t)r * DHEAD + off);
    if (!sel) {
      float w = __expf(B - A[(size_t)h * SQLEN + t0 + r]);
      bf16x8 o;
#pragma unroll
      for (int j = 0; j < 8; j++) o[j] = (short)f2bf(bf2f((unsigned short)in[j]) * w);
      *(bf16x8*)&tile[r][off] = o;
    } else {
      *(bf16x8*)&tile[r][off] = in;
    }
  }
  __syncthreads();
#pragma unroll
  for (int p = 0; p < 2; p++) {
    int c = tid + p * 256;
    int dr = c >> 3, toff = (c & 7) * 8;
    bf16x8 o;
#pragma unroll
    for (int j = 0; j < 8; j++) o[j] = (short)tile[toff + j][dr];
    *(bf16x8*)(dst + (size_t)dr * SQLEN + toff) = o;
  }
}

// ---------------- transpose state -> stT bf16 [h][e][d] ---------------------
__global__ __launch_bounds__(256) void transpose_state_kernel(const float* __restrict__ st,
                                                              unsigned short* __restrict__ stT) {
  __shared__ float tile[64][65];
  int h = blockIdx.z, d0 = blockIdx.x * 64, e0 = blockIdx.y * 64;
  int tid = threadIdx.x;
  const float* src = st + (size_t)h * 16384 + (size_t)d0 * DHEAD + e0;
#pragma unroll
  for (int p = 0; p < 4; p++) {
    int idx = tid + p * 256;
    int r = idx >> 4, c = (idx & 15) * 4;
    float4 f = *(const float4*)(src + (size_t)r * DHEAD + c);
    tile[r][c] = f.x; tile[r][c + 1] = f.y; tile[r][c + 2] = f.z; tile[r][c + 3] = f.w;
  }
  __syncthreads();
  unsigned short* dst = stT + (size_t)h * 16384 + (size_t)e0 * DHEAD + d0;
#pragma unroll
  for (int p = 0; p < 2; p++) {
    int idx = tid + p * 256;
    int er = idx >> 3, doff = (idx & 7) * 8;
    bf16x8 o;
#pragma unroll
    for (int j = 0; j < 8; j++) o[j] = (short)f2bf(tile[doff + j][er]);
    *(bf16x8*)(dst + (size_t)er * DHEAD + doff) = o;
  }
}

// ---------------- retention v8: split-j x2, private buffers, no atomics -----
__global__ __launch_bounds__(256) void retention_split(const unsigned short* __restrict__ qb,
                                                       const unsigned short* __restrict__ kb,
                                                       const unsigned short* __restrict__ vT,
                                                       const unsigned short* __restrict__ stT,
                                                       const float* __restrict__ A,
                                                       float* __restrict__ R32) {
  __shared__ __align__(16) unsigned short ks[2][64 * 128];
  __shared__ __align__(16) unsigned short vs[2][128 * 64];
  __shared__ __align__(16) unsigned short Ss[64 * 72];
  int h = blockIdx.x;
  int i0 = blockIdx.y * 64;
  int jc = blockIdx.z;
  int jlo = jc * 1024;
  int jhi = min(i0, jlo + 960);         // last j-tile start in this chunk
  int tid = threadIdx.x;
  int wave = tid >> 6, lane = tid & 63, quad = lane >> 4, m16 = lane & 15;
  const float* Ah = A + (size_t)h * SQLEN;
  float c = Ah[i0];
  int rq = wave * 16 + m16;
  float* Rc = R32 + (size_t)jc * 4194304;   // private slab per chunk

  // wave-parallel scan for first non-skipped j-tile (prefix is monotone)
  bool skipl = false;
  if (lane < 32) {
    int j0l = lane * 64;
    if (j0l <= i0) skipl = (c - Ah[j0l + 63] < -87.f);
  }
  unsigned long long smask = __ballot(skipl);
  int j_start = 64 * (int)__builtin_ctzll(~smask);
  int j_begin = max(j_start, jlo);
  bool work = (jlo <= i0) && (j_begin <= jhi);   // uniform
  bool crossw = (jc == 0) && (c > -87.f);        // uniform

  floatx4 acc[8];
#pragma unroll
  for (int et = 0; et < 8; et++) acc[et] = (floatx4){0.f, 0.f, 0.f, 0.f};

  if (work || crossw) {
    const unsigned short* qh = qb + ((size_t)h * SQLEN + i0 + rq) * DHEAD;
    bf16x8 qf[4];
#pragma unroll
    for (int dc = 0; dc < 4; dc++)
      qf[dc] = *(const bf16x8*)(qh + dc * 32 + quad * 8);
    float ei = __expf(Ah[i0 + rq] - c);

    const unsigned short* khb = kb + (size_t)h * SQLEN * DHEAD;
    const unsigned short* vhb = vT + (size_t)h * (DHEAD * SQLEN);

#define STAGE_KV(b_, j0_) do { \
    const unsigned short* kh_ = khb + (size_t)(j0_) * DHEAD; \
    const unsigned short* vh_ = vhb + (j0_); \
    _Pragma("unroll") for (int p = 0; p < 4; p++) { \
      int cch = tid + p * 256; \
      int r_ = cch >> 4, kp_ = (cch & 15) ^ (r_ & 7); \
      GLD(kh_ + (size_t)r_ * DHEAD + kp_ * 8, &ks[b_][0] + cch * 8); \
      int e_ = cch >> 3, tp_ = (cch & 7) ^ (e_ & 7); \
      GLD(vh_ + (size_t)e_ * SQLEN + tp_ * 8, &vs[b_][0] + cch * 8); \
    } \
  } while (0)

    if (work) STAGE_KV(0, j_begin);     // latency hides under cross term

    if (crossw) {
      const unsigned short* sp = stT + (size_t)h * 16384;
      float ecr[4];
#pragma unroll
      for (int r = 0; r < 4; r++) ecr[r] = __expf(Ah[i0 + wave * 16 + quad * 4 + r]);
#pragma unroll
      for (int et = 0; et < 8; et++) {
#pragma unroll
        for (int dc = 0; dc < 4; dc++) {
          bf16x8 sf = *(const bf16x8*)(sp + (et * 16 + m16) * DHEAD + dc * 32 + quad * 8);
          acc[et] = __builtin_amdgcn_mfma_f32_16x16x32_bf16(qf[dc], sf, acc[et], 0, 0, 0);
        }
#pragma unroll
        for (int r = 0; r < 4; r++) acc[et][r] *= ecr[r];
      }
    }

    if (work) {
      int cur = 0;
      for (int j0 = j_begin; j0 <= jhi; j0 += 64) {
        int nxt = j0 + 64;
        // decay source issued BEFORE the staging GLDs (v6 lesson): the loop's
        // vmem window after this point is exactly the 8 GLDs.
        float av = Ah[j0 + lane];
        __builtin_amdgcn_sched_barrier(0);
        if (nxt <= jhi) {
          STAGE_KV(cur ^ 1, nxt);
          asm volatile("s_waitcnt vmcnt(8) lgkmcnt(0)" ::: "memory");
        } else {
          asm volatile("s_waitcnt vmcnt(0) lgkmcnt(0)" ::: "memory");
        }
        __builtin_amdgcn_sched_barrier(0);
        asm volatile("s_barrier" ::: "memory");  // cur landed globally

        float dj = __expf(c - av);

        bool diag = (j0 == i0);
        const unsigned short* ksc = &ks[cur][0];
        const unsigned short* vsc = &vs[cur][0];
#pragma unroll
        for (int jt = 0; jt < 4; jt++) {
          floatx4 s = (floatx4){0.f, 0.f, 0.f, 0.f};
#pragma unroll
          for (int dc = 0; dc < 4; dc++) {
            int rk = jt * 16 + m16;
            bf16x8 kf = *(const bf16x8*)(ksc + rk * 128 + (((dc * 4 + quad) ^ (rk & 7)) * 8));
            s = __builtin_amdgcn_mfma_f32_16x16x32_bf16(kf, qf[dc], s, 0, 0, 0);
          }
          int jb = jt * 16 + quad * 4;
          float d0 = __shfl(dj, jb + 0);
          float d1 = __shfl(dj, jb + 1);
          float d2 = __shfl(dj, jb + 2);
          float d3 = __shfl(dj, jb + 3);
          ushort4 pk;
          pk.x = f2bf((diag && (jb + 0 > rq)) ? 0.f : s[0] * ei * d0);
          pk.y = f2bf((diag && (jb + 1 > rq)) ? 0.f : s[1] * ei * d1);
          pk.z = f2bf((diag && (jb + 2 > rq)) ? 0.f : s[2] * ei * d2);
          pk.w = f2bf((diag && (jb + 3 > rq)) ? 0.f : s[3] * ei * d3);
          *(ushort4*)(Ss + rq * 72 + jb) = pk;
        }

        bf16x8 sfr[2];
#pragma unroll
        for (int kc = 0; kc < 2; kc++)
          sfr[kc] = *(const bf16x8*)(Ss + rq * 72 + kc * 32 + quad * 8);
#pragma unroll
        for (int et = 0; et < 8; et++) {
#pragma unroll
          for (int kc = 0; kc < 2; kc++) {
            int e = et * 16 + m16;
            bf16x8 vf = *(const bf16x8*)(vsc + e * 64 + (((kc * 4 + quad) ^ (e & 7)) * 8));
            acc[et] = __builtin_amdgcn_mfma_f32_16x16x32_bf16(sfr[kc], vf, acc[et], 0, 0, 0);
          }
        }
        asm volatile("s_barrier" ::: "memory");
        cur ^= 1;
      }
    }
#undef STAGE_KV
  }

  // plain stores into this chunk's private slab (zeros if no work)
#pragma unroll
  for (int r = 0; r < 4; r++) {
    int row = i0 + wave * 16 + quad * 4 + r;
    size_t o = (size_t)row * DMODEL + h * DHEAD;
#pragma unroll
    for (int et = 0; et < 8; et++)
      Rc[o + et * 16 + m16] = acc[et][r];
  }
}

// ------ group norm over R32[0]+R32[1] -> rn fp32 + rnb bf16 -----------------
__global__ __launch_bounds__(256) void gn_kernel(const float* __restrict__ R32,
                                                 const float* __restrict__ gn_w,
                                                 const float* __restrict__ gn_b,
                                                 float* __restrict__ rn,
                                                 unsigned short* __restrict__ rnb) {
  int row = blockIdx.x;
  int tid = threadIdx.x;
  size_t base = (size_t)row * DMODEL + tid * 8;
  float4 a0 = *(const float4*)(R32 + base);
  float4 b0 = *(const float4*)(R32 + base + 4);
  float4 a1 = *(const float4*)(R32 + 4194304 + base);
  float4 b1 = *(const float4*)(R32 + 4194304 + base + 4);
  float v[8] = {a0.x + a1.x, a0.y + a1.y, a0.z + a1.z, a0.w + a1.w,
                b0.x + b1.x, b0.y + b1.y, b0.z + b1.z, b0.w + b1.w};
  float s = 0.f, ss = 0.f;
#pragma unroll
  for (int k = 0; k < 8; k++) { s += v[k]; ss += v[k] * v[k]; }
  // reduce across the 16 threads of this head (tid bits 0-3, same wave)
#pragma unroll
  for (int off = 8; off > 0; off >>= 1) {
    s += __shfl_xor(s, off);
    ss += __shfl_xor(ss, off);
  }
  float mu = s * (1.f / 128.f);
  float var = ss * (1.f / 128.f) - mu * mu;
  float inv = rsqrtf(var + 1e-5f);
  int col0 = tid * 8;
  const float* wp = gn_w + col0;
  const float* bp = gn_b + col0;
  float o[8];
  ushort4 ob[2];
#pragma unroll
  for (int k = 0; k < 8; k++) {
    o[k] = (v[k] - mu) * inv * wp[k] + bp[k];
    ((unsigned short*)ob)[k] = f2bf(o[k]);
  }
  float* rp = rn + (size_t)row * DMODEL + col0;
  *(float4*)rp = (float4){o[0], o[1], o[2], o[3]};
  *(float4*)(rp + 4) = (float4){o[4], o[5], o[6], o[7]};
  *(ushort4*)(rnb + (size_t)row * DMODEL + col0) = ob[0];
  *(ushort4*)(rnb + (size_t)row * DMODEL + col0 + 4) = ob[1];
}

// -------- new_state GEMM: P[h,chunk] = kT_s[:,krange] @ vT[:,krange]^T ------
__global__ __launch_bounds__(256) void state_gemm(const unsigned short* __restrict__ kT,
                                                  const unsigned short* __restrict__ vT,
                                                  float* __restrict__ P) {
  __shared__ __align__(16) unsigned short As[128 * 32];
  __shared__ __align__(16) unsigned short Bs[128 * 32];
  int chunk = blockIdx.x, h = blockIdx.y;
  int tid = threadIdx.x;
  int wave = tid >> 6, lane = tid & 63;
  int wm = wave >> 1, wn = wave & 1;
  int quad = lane >> 4, m16 = lane & 15;
  const unsigned short* Ab = kT + (size_t)h * (DHEAD * SQLEN);
  const unsigned short* Bb = vT + (size_t)h * (DHEAD * SQLEN);

  floatx4 acc[4][4];
#pragma unroll
  for (int i = 0; i < 4; i++)
#pragma unroll
    for (int j = 0; j < 4; j++) acc[i][j] = (floatx4){0.f, 0.f, 0.f, 0.f};

  int c0 = tid, c1 = tid + 256;
  int r0c = c0 >> 2, q0c = (c0 & 3) * 8;
  int r1c = c1 >> 2, q1c = (c1 & 3) * 8;

  for (int k0 = chunk * 256; k0 < chunk * 256 + 256; k0 += 32) {
    __builtin_amdgcn_global_load_lds(
        (const __attribute__((address_space(1))) unsigned int*)(Ab + (size_t)r0c * SQLEN + k0 + q0c),
        (__attribute__((address_space(3))) unsigned int*)(As + c0 * 8), 16, 0, 0);
    __builtin_amdgcn_global_load_lds(
        (const __attribute__((address_space(1))) unsigned int*)(Ab + (size_t)r1c * SQLEN + k0 + q1c),
        (__attribute__((address_space(3))) unsigned int*)(As + c1 * 8), 16, 0, 0);
    __builtin_amdgcn_global_load_lds(
        (const __attribute__((address_space(1))) unsigned int*)(Bb + (size_t)r0c * SQLEN + k0 + q0c),
        (__attribute__((address_space(3))) unsigned int*)(Bs + c0 * 8), 16, 0, 0);
    __builtin_amdgcn_global_load_lds(
        (const __attribute__((address_space(1))) unsigned int*)(Bb + (size_t)r1c * SQLEN + k0 + q1c),
        (__attribute__((address_space(3))) unsigned int*)(Bs + c1 * 8), 16, 0, 0);
    __syncthreads();

    bf16x8 af[4], bfr[4];
#pragma unroll
    for (int i = 0; i < 4; i++)
      af[i] = *(const bf16x8*)(As + (wm * 64 + i * 16 + m16) * 32 + quad * 8);
#pragma unroll
    for (int j = 0; j < 4; j++)
      bfr[j] = *(const bf16x8*)(Bs + (wn * 64 + j * 16 + m16) * 32 + quad * 8);
#pragma unroll
    for (int i = 0; i < 4; i++)
#pragma unroll
      for (int j = 0; j < 4; j++)
        acc[i][j] = __builtin_amdgcn_mfma_f32_16x16x32_bf16(af[i], bfr[j], acc[i][j], 0, 0, 0);
    __syncthreads();
  }

  float* Pp = P + (size_t)(h * 8 + chunk) * 16384;
#pragma unroll
  for (int i = 0; i < 4; i++)
#pragma unroll
    for (int j = 0; j < 4; j++) {
      int rr = wm * 64 + i * 16 + quad * 4;
      int cc = wn * 64 + j * 16 + m16;
#pragma unroll
      for (int r = 0; r < 4; r++)
        Pp[(size_t)(rr + r) * DHEAD + cc] = acc[i][j][r];
    }
}

__global__ __launch_bounds__(256) void state_combine(const float* __restrict__ P,
                                                     const float* __restrict__ state,
                                                     const float* __restrict__ A,
                                                     float* __restrict__ out_state) {
  int idx = blockIdx.x * 256 + threadIdx.x;
  int h = idx >> 14;
  int de = idx & 16383;
  float B = A[(size_t)h * SQLEN + SQLEN - 1];
  float s = __expf(B) * state[idx];
#pragma unroll
  for (int c = 0; c < 8; c++) s += P[(size_t)(h * 8 + c) * 16384 + de];
  out_state[idx] = s;
}

extern "C" void kernel_launch(void* const* d_in, const int* in_sizes, int n_in,
                              void* d_out, int out_size, void* d_ws, size_t ws_size,
                              hipStream_t stream) {
  const float* x = (const float*)d_in[0];
  const float* state = (const float*)d_in[1];
  const float* W_qkv = (const float*)d_in[2];
  const float* W_alpha = (const float*)d_in[3];
  const float* b_alpha = (const float*)d_in[4];
  const float* alpha_base = (const float*)d_in[5];
  const float* gn_w = (const float*)d_in[6];
  const float* gn_b = (const float*)d_in[7];
  const float* W_out = (const float*)d_in[8];
  const float* W_gate = (const float*)d_in[9];
  const int* offset = (const int*)d_in[10];

  float* ws = (float*)d_ws;
  float* qkv = ws;                      // [0,12582912) alive gemm -> xpos
  float* P   = ws;                      // [0,2097152) after retention (qkv dead)
  float* R32 = ws + 4194304;            // 2 slabs: [4194304,12582912) after xpos
  float* rn  = ws + 29360128;
  float* araw = ws + 33554432;
  float* Acum = ws + 33587200;

  unsigned short* xb    = (unsigned short*)(ws + 12582912);
  unsigned short* Wqkvb = (unsigned short*)(ws + 16777216);
  unsigned short* qb    = (unsigned short*)(ws + 12582912);
  unsigned short* kb    = (unsigned short*)(ws + 14680064);
  unsigned short* vb    = (unsigned short*)(ws + 16777216);
  unsigned short* kT_s  = (unsigned short*)(ws + 18874368);
  unsigned short* vT_b  = (unsigned short*)(ws + 20971520);
  unsigned short* stT_b = (unsigned short*)(ws + 23068672);
  unsigned short* rnb   = (unsigned short*)(ws + 25165824);
  unsigned short* Wgateb = (unsigned short*)(ws + 14680064);
  unsigned short* Woutb  = (unsigned short*)(ws + 16777216);
  unsigned short* Hb     = (unsigned short*)(ws + 18874368);

  float* out = (float*)d_out;
  float* out_state = out + 4194304;

  dim3 blk(256);
  f2b2_kernel<<<dim3(16384), blk, 0, stream>>>((const float4*)x, (ushort4*)xb,
                                               (const float4*)W_qkv, (ushort4*)Wqkvb, 4096);
  gemm256_nt<<<dim3(24, 8), dim3(512), 0, stream>>>(xb, Wqkvb, qkv, 2048, 6144, 2048);

  alpha_kernel<<<dim3(512), blk, 0, stream>>>(x, W_alpha, b_alpha, alpha_base, araw);
  cumsum_kernel<<<dim3(16), blk, 0, stream>>>(araw, Acum);
  xpos_kernel<<<dim3(8192), blk, 0, stream>>>(qkv, araw, offset, qb, kb, vb);
  transpose_kv_kernel<<<dim3(32, 2, 32), blk, 0, stream>>>(kb, vb, Acum, kT_s, vT_b);
  transpose_state_kernel<<<dim3(2, 2, 16), blk, 0, stream>>>(state, stT_b);

  retention_split<<<dim3(16, 32, 2), blk, 0, stream>>>(qb, kb, vT_b, stT_b, Acum, R32);
  gn_kernel<<<dim3(2048), blk, 0, stream>>>(R32, gn_w, gn_b, rn, rnb);

  state_gemm<<<dim3(8, 16), blk, 0, stream>>>(kT_s, vT_b, P);
  state_combine<<<dim3(1024), blk, 0, stream>>>(P, state, Acum, out_state);

  f2b2_kernel<<<dim3(8192), blk, 0, stream>>>((const float4*)W_gate, (ushort4*)Wgateb,
                                              (const float4*)W_out, (ushort4*)Woutb, 4096);
  // tail GEMMs: 128x64 tiles (512 blocks = 2/CU) + dbuf counted-vmcnt K-loop
  gemm_tail_swish<<<dim3(32, 16), blk, 0, stream>>>(rnb, Wgateb, rn, Hb, 2048, 2048, 2048);
  gemm_tail_out<<<dim3(32, 16), blk, 0, stream>>>(Hb, Woutb, out, 2048, 2048, 2048);
}